// Round 7
// baseline (2105.709 us; speedup 1.0000x reference)
//
#include <hip/hip_runtime.h>
#include <hip/hip_bf16.h>
#include <hip/hip_fp16.h>

#define N_NODES 100000
#define N_EDGES 1600000
#define DIM_IN 128
#define DIM_OUT 64

#define ROWB 128    // rows per bucket
#define NB2 782     // buckets: row >> 7 (ceil(100000/128))
#define NCHUNK 391  // edge chunks
#define CHUNK 4096  // edges per chunk (NCHUNK*CHUNK >= N_EDGES)
#define BCAP2 2560  // max edges per bucket (mean 2046, Poisson sd ~45)

typedef unsigned int uint;
typedef unsigned short ushort;
typedef _Float16 half8 __attribute__((ext_vector_type(8)));
typedef float f32x4 __attribute__((ext_vector_type(4)));

__device__ inline ushort f2h(float f) {
    __half h = __float2half(f);  // round-to-nearest-even
    return *reinterpret_cast<ushort*>(&h);
}

// ---------------- CSR-ish build: bucket (row>>7), then col-group sort ----------------

// A: per-chunk histogram over buckets. counts[b * NCHUNK + c]
__global__ __launch_bounds__(256) void chunk_hist_kernel(const int* __restrict__ erow,
                                                         int* __restrict__ counts, int E) {
    __shared__ int hist[NB2];
    const int t = threadIdx.x, c = blockIdx.x;
    for (int b = t; b < NB2; b += 256) hist[b] = 0;
    __syncthreads();
    const int eb = c * CHUNK;
#pragma unroll
    for (int i = 0; i < CHUNK / 256; ++i) {
        int e = eb + i * 256 + t;
        if (e < E) atomicAdd(&hist[erow[e] >> 7], 1);
    }
    __syncthreads();
    for (int b = t; b < NB2; b += 256) counts[b * NCHUNK + c] = hist[b];
}

// B1: per-bucket exclusive scan over chunks
__global__ __launch_bounds__(512) void bucket_scan_kernel(const int* __restrict__ counts,
                                                          int* __restrict__ offnb,
                                                          int* __restrict__ tot) {
    __shared__ int s[512];
    const int b = blockIdx.x, t = threadIdx.x;
    int v = (t < NCHUNK) ? counts[b * NCHUNK + t] : 0;
    s[t] = v;
    __syncthreads();
#pragma unroll
    for (int o = 1; o < 512; o <<= 1) {
        int x = s[t];
        int y = (t >= o) ? s[t - o] : 0;
        __syncthreads();
        s[t] = x + y;
        __syncthreads();
    }
    if (t < NCHUNK) offnb[b * NCHUNK + t] = s[t] - v;
    if (t == 511) tot[b] = s[511];
}

// B2: exclusive scan over NB2 buckets (2 elems/thread)
__global__ __launch_bounds__(512) void base_scan_kernel(const int* __restrict__ tot,
                                                        int* __restrict__ bbase, int E) {
    __shared__ int s[512];
    const int t = threadIdx.x;
    int i0 = 2 * t, i1 = 2 * t + 1;
    int v0 = (i0 < NB2) ? tot[i0] : 0;
    int v1 = (i1 < NB2) ? tot[i1] : 0;
    int sum = v0 + v1;
    s[t] = sum;
    __syncthreads();
#pragma unroll
    for (int o = 1; o < 512; o <<= 1) {
        int x = s[t];
        int y = (t >= o) ? s[t - o] : 0;
        __syncthreads();
        s[t] = x + y;
        __syncthreads();
    }
    int excl = s[t] - sum;
    if (i0 < NB2) bbase[i0] = excl;
    if (i1 < NB2) bbase[i1] = excl + v0;
    if (t == 0) bbase[NB2] = E;
}

// C: coarse scatter by bucket. key = (row&127)<<17 | col ; val separate.
__global__ __launch_bounds__(512) void coarse_scatter_kernel(const int* __restrict__ erow,
                                                             const int* __restrict__ ecol,
                                                             const float* __restrict__ eval,
                                                             const int* __restrict__ offnb,
                                                             const int* __restrict__ bbase,
                                                             uint* __restrict__ keyOut,
                                                             float* __restrict__ valOut, int E) {
    __shared__ int hist[NB2];
    __shared__ int segOff[NB2];
    __shared__ int localOff[NB2];
    __shared__ int sc[512];
    __shared__ int idxL[CHUNK];
    __shared__ int gaddrL[CHUNK];

    const int t = threadIdx.x, c = blockIdx.x;
    for (int b = t; b < NB2; b += 512) {
        hist[b] = 0;
        segOff[b] = bbase[b] + offnb[b * NCHUNK + c];
    }
    __syncthreads();
    const int eb = c * CHUNK;
    uint bq[CHUNK / 512];
#pragma unroll
    for (int i = 0; i < CHUNK / 512; ++i) {
        int e = eb + i * 512 + t;
        if (e < E) {
            int b = erow[e] >> 7;
            int q = atomicAdd(&hist[b], 1);
            bq[i] = ((uint)b << 16) | (uint)q;
        } else {
            bq[i] = 0xFFFFFFFFu;
        }
    }
    __syncthreads();
    // exclusive scan of hist over NB2 (2 elems/thread)
    int i0 = 2 * t, i1 = 2 * t + 1;
    int v0 = (i0 < NB2) ? hist[i0] : 0;
    int v1 = (i1 < NB2) ? hist[i1] : 0;
    int sum = v0 + v1;
    sc[t] = sum;
    __syncthreads();
#pragma unroll
    for (int o = 1; o < 512; o <<= 1) {
        int x = sc[t];
        int y = (t >= o) ? sc[t - o] : 0;
        __syncthreads();
        sc[t] = x + y;
        __syncthreads();
    }
    int excl = sc[t] - sum;
    if (i0 < NB2) localOff[i0] = excl;
    if (i1 < NB2) localOff[i1] = excl + v0;
    __syncthreads();
#pragma unroll
    for (int i = 0; i < CHUNK / 512; ++i) {
        if (bq[i] != 0xFFFFFFFFu) {
            int b = bq[i] >> 16;
            int q = bq[i] & 0xFFFF;
            int s = localOff[b] + q;
            idxL[s] = eb + i * 512 + t;
            gaddrL[s] = segOff[b] + q;
        }
    }
    __syncthreads();
    const int m = min(CHUNK, E - eb);
    for (int s = t; s < m; s += 512) {
        int e = idxL[s];
        int g = gaddrL[s];
        keyOut[g] = ((uint)(erow[e] & (ROWB - 1)) << 17) | (uint)ecol[e];
        valOut[g] = eval[e];
    }
}

// D: sort each bucket's edges by column group (col>>9, 196 bins) -> ep (key,val)
__global__ __launch_bounds__(256) void colsort_kernel(const uint* __restrict__ keyIn,
                                                      const float* __restrict__ valIn,
                                                      const int* __restrict__ bbase,
                                                      int2* __restrict__ ep) {
    __shared__ uint keyL[BCAP2];
    __shared__ float valL[BCAP2];
    __shared__ int hist[256];
    __shared__ int offs[256];
    const int b = blockIdx.x, t = threadIdx.x;
    const int s0 = bbase[b], s1 = bbase[b + 1];
    const int m = min(s1 - s0, BCAP2);
    hist[t] = 0;
    __syncthreads();
    for (int j = t; j < m; j += 256) {
        uint k = keyIn[s0 + j];
        keyL[j] = k;
        valL[j] = valIn[s0 + j];
        atomicAdd(&hist[(k & 0x1FFFFu) >> 9], 1);
    }
    __syncthreads();
    int v = hist[t];
    offs[t] = v;
    __syncthreads();
#pragma unroll
    for (int o = 1; o < 256; o <<= 1) {
        int x = offs[t];
        int y = (t >= o) ? offs[t - o] : 0;
        __syncthreads();
        offs[t] = x + y;
        __syncthreads();
    }
    int excl = offs[t] - v;
    __syncthreads();
    hist[t] = excl;  // running cursor
    __syncthreads();
    for (int j = t; j < m; j += 256) {
        uint k = keyL[j];
        int pos = atomicAdd(&hist[(k & 0x1FFFFu) >> 9], 1);
        ep[s0 + pos] = make_int2((int)k, __float_as_int(valL[j]));
    }
}

// ---------------- f32 -> f16 conversion (8 elems/thread) ----------------

__global__ __launch_bounds__(256) void cvt_f16_kernel(const float* __restrict__ in,
                                                      uint* __restrict__ outp, int n8) {
    int i = blockIdx.x * 256 + threadIdx.x;
    if (i >= n8) return;
    const float4* in4 = reinterpret_cast<const float4*>(in) + (size_t)i * 2;
    float4 a = in4[0];
    float4 b = in4[1];
    uint4 o;
    o.x = (uint)f2h(a.x) | ((uint)f2h(a.y) << 16);
    o.y = (uint)f2h(a.z) | ((uint)f2h(a.w) << 16);
    o.z = (uint)f2h(b.x) | ((uint)f2h(b.y) << 16);
    o.w = (uint)f2h(b.z) | ((uint)f2h(b.w) << 16);
    reinterpret_cast<uint4*>(outp)[i] = o;
}

// ---------------- SpMM layer 1, bucket-blocked: LDS f32 accumulate ----------------
// Block b owns rows [b*128, b*128+128). Edges of the bucket are col-group sorted, so
// all resident blocks sweep the Xh table in the same column order -> L2-resident window.
// LDS agg swizzle: dim 2l -> pos l, dim 2l+1 -> pos 64+l (conflict-free ds_add_f32).

__global__ __launch_bounds__(256) void spmm1_blocked_kernel(const int2* __restrict__ ep,
                                                            const int* __restrict__ bbase,
                                                            const uint* __restrict__ Xh,
                                                            uint* __restrict__ aggh) {
    __shared__ float sAgg[ROWB * 128];
    const int t = threadIdx.x, b = blockIdx.x;
    const int l = t & 63, w = t >> 6;
#pragma unroll
    for (int i = 0; i < 64; ++i) sAgg[i * 256 + t] = 0.f;
    __syncthreads();
    const int s0 = bbase[b], s1 = bbase[b + 1];
    int e = s0 + w;
    for (; e + 28 < s1; e += 32) {  // wave handles e, e+4, ..., e+28
        int2 cv[8];
        uint xu[8];
#pragma unroll
        for (int i = 0; i < 8; ++i) cv[i] = ep[e + 4 * i];
#pragma unroll
        for (int i = 0; i < 8; ++i) xu[i] = Xh[(size_t)(cv[i].x & 0x1FFFF) * 64 + l];
#pragma unroll
        for (int i = 0; i < 8; ++i) {
            float v = __int_as_float(cv[i].y);
            int row = (cv[i].x >> 17) & (ROWB - 1);
            __half2 h2 = *reinterpret_cast<__half2*>(&xu[i]);
            float2 f = __half22float2(h2);
            atomicAdd(&sAgg[row * 128 + l], v * f.x);
            atomicAdd(&sAgg[row * 128 + 64 + l], v * f.y);
        }
    }
    for (; e < s1; e += 4) {
        int2 cv = ep[e];
        uint xu = Xh[(size_t)(cv.x & 0x1FFFF) * 64 + l];
        float v = __int_as_float(cv.y);
        int row = (cv.x >> 17) & (ROWB - 1);
        __half2 h2 = *reinterpret_cast<__half2*>(&xu);
        float2 f = __half22float2(h2);
        atomicAdd(&sAgg[row * 128 + l], v * f.x);
        atomicAdd(&sAgg[row * 128 + 64 + l], v * f.y);
    }
    __syncthreads();
    const int row0 = b * ROWB;
#pragma unroll
    for (int i = 0; i < 32; ++i) {
        int fid = i * 256 + t;
        int row = fid >> 6, q = fid & 63;
        int gr = row0 + row;
        if (gr < N_NODES)
            aggh[(size_t)gr * 64 + q] =
                (uint)f2h(sAgg[row * 128 + q]) | ((uint)f2h(sAgg[row * 128 + 64 + q]) << 16);
    }
}

// ---------------- SpMM layer 2, bucket-blocked + tanh epilogue ----------------

__global__ __launch_bounds__(256) void spmm2_blocked_kernel(const int2* __restrict__ ep,
                                                            const int* __restrict__ bbase,
                                                            const ushort* __restrict__ Ph,
                                                            float* __restrict__ out) {
    __shared__ float sAgg[ROWB * 64];
    const int t = threadIdx.x, b = blockIdx.x;
    const int l = t & 63, w = t >> 6;
#pragma unroll
    for (int i = 0; i < 32; ++i) sAgg[i * 256 + t] = 0.f;
    __syncthreads();
    const int s0 = bbase[b], s1 = bbase[b + 1];
    int e = s0 + w;
    for (; e + 28 < s1; e += 32) {
        int2 cv[8];
        ushort xu[8];
#pragma unroll
        for (int i = 0; i < 8; ++i) cv[i] = ep[e + 4 * i];
#pragma unroll
        for (int i = 0; i < 8; ++i) xu[i] = Ph[(size_t)(cv[i].x & 0x1FFFF) * 64 + l];
#pragma unroll
        for (int i = 0; i < 8; ++i) {
            float v = __int_as_float(cv[i].y);
            int row = (cv[i].x >> 17) & (ROWB - 1);
            __half h = *reinterpret_cast<__half*>(&xu[i]);
            atomicAdd(&sAgg[row * 64 + l], v * __half2float(h));
        }
    }
    for (; e < s1; e += 4) {
        int2 cv = ep[e];
        ushort u = Ph[(size_t)(cv.x & 0x1FFFF) * 64 + l];
        float v = __int_as_float(cv.y);
        int row = (cv.x >> 17) & (ROWB - 1);
        __half h = *reinterpret_cast<__half*>(&u);
        atomicAdd(&sAgg[row * 64 + l], v * __half2float(h));
    }
    __syncthreads();
    const int row0 = b * ROWB;
#pragma unroll
    for (int i = 0; i < 8; ++i) {
        int fid = i * 256 + t;
        int row = fid >> 4, q = fid & 15;
        int gr = row0 + row;
        if (gr < N_NODES) {
            float4 v;
            v.x = tanhf(sAgg[row * 64 + q * 4 + 0]);
            v.y = tanhf(sAgg[row * 64 + q * 4 + 1]);
            v.z = tanhf(sAgg[row * 64 + q * 4 + 2]);
            v.w = tanhf(sAgg[row * 64 + q * 4 + 3]);
            *reinterpret_cast<float4*>(&out[(size_t)gr * 64 + q * 4]) = v;
        }
    }
}

// ---------------- Fused MLP: P = tanh(agg @ W1^T) @ W2^T, all f16 MFMA ----------------

__global__ __launch_bounds__(256) void fused_mlp_kernel(const uint* __restrict__ Ah,
                                                        const uint* __restrict__ W1h,
                                                        const uint* __restrict__ W2h,
                                                        uint* __restrict__ Ph, int M) {
    __shared__ __align__(16) ushort sA[128 * 128];   // agg tile, then H
    __shared__ __align__(16) ushort sW1[128 * 128];  // W1, then P
    __shared__ __align__(16) ushort sW2[64 * 128];

    const int t = threadIdx.x;
    const int l = t & 63;
    const int w = t >> 6;
    const int row0 = blockIdx.x * 128;
    const int lr = l & 15;
    const int lk = l >> 4;

#pragma unroll
    for (int i = 0; i < 8; ++i) {
        int fid = i * 256 + t;
        int row = fid >> 4, slot = fid & 15;
        int gr = row0 + row;
        uint4 v = make_uint4(0, 0, 0, 0);
        if (gr < M) v = reinterpret_cast<const uint4*>(Ah)[(size_t)gr * 16 + slot];
        *reinterpret_cast<uint4*>(&sA[row * 128 + ((slot ^ (row & 7)) << 3)]) = v;
    }
#pragma unroll
    for (int i = 0; i < 8; ++i) {
        int fid = i * 256 + t;
        int row = fid >> 4, slot = fid & 15;
        uint4 v = reinterpret_cast<const uint4*>(W1h)[row * 16 + slot];
        *reinterpret_cast<uint4*>(&sW1[row * 128 + ((slot ^ (row & 7)) << 3)]) = v;
    }
#pragma unroll
    for (int i = 0; i < 4; ++i) {
        int fid = i * 256 + t;
        int row = fid >> 4, slot = fid & 15;
        uint4 v = reinterpret_cast<const uint4*>(W2h)[row * 16 + slot];
        *reinterpret_cast<uint4*>(&sW2[row * 128 + ((slot ^ (row & 7)) << 3)]) = v;
    }
    __syncthreads();

    f32x4 acc[2][8];
#pragma unroll
    for (int rf = 0; rf < 2; ++rf)
#pragma unroll
        for (int cf = 0; cf < 8; ++cf) acc[rf][cf] = (f32x4){0.f, 0.f, 0.f, 0.f};

    half8 aF[2][4];
#pragma unroll
    for (int rf = 0; rf < 2; ++rf) {
        int row = w * 32 + rf * 16 + lr;
#pragma unroll
        for (int kc = 0; kc < 4; ++kc) {
            int slot = kc * 4 + lk;
            aF[rf][kc] = *reinterpret_cast<const half8*>(&sA[row * 128 + ((slot ^ (row & 7)) << 3)]);
        }
    }
#pragma unroll
    for (int cf = 0; cf < 8; ++cf) {
        int col = cf * 16 + lr;
#pragma unroll
        for (int kc = 0; kc < 4; ++kc) {
            int slot = kc * 4 + lk;
            half8 bF = *reinterpret_cast<const half8*>(&sW1[col * 128 + ((slot ^ (col & 7)) << 3)]);
            acc[0][cf] = __builtin_amdgcn_mfma_f32_16x16x32_f16(aF[0][kc], bF, acc[0][cf], 0, 0, 0);
            acc[1][cf] = __builtin_amdgcn_mfma_f32_16x16x32_f16(aF[1][kc], bF, acc[1][cf], 0, 0, 0);
        }
    }
    __syncthreads();

#pragma unroll
    for (int rf = 0; rf < 2; ++rf)
#pragma unroll
        for (int cf = 0; cf < 8; ++cf)
#pragma unroll
            for (int reg = 0; reg < 4; ++reg) {
                int row = w * 32 + rf * 16 + lk * 4 + reg;
                int col = cf * 16 + lr;
                sA[row * 128 + (((col >> 3) ^ (row & 7)) << 3) + (col & 7)] =
                    f2h(tanhf(acc[rf][cf][reg]));
            }
    __syncthreads();

    f32x4 acc2[2][4];
#pragma unroll
    for (int rf = 0; rf < 2; ++rf)
#pragma unroll
        for (int cf = 0; cf < 4; ++cf) acc2[rf][cf] = (f32x4){0.f, 0.f, 0.f, 0.f};
#pragma unroll
    for (int rf = 0; rf < 2; ++rf) {
        int row = w * 32 + rf * 16 + lr;
#pragma unroll
        for (int kc = 0; kc < 4; ++kc) {
            int slot = kc * 4 + lk;
            aF[rf][kc] = *reinterpret_cast<const half8*>(&sA[row * 128 + ((slot ^ (row & 7)) << 3)]);
        }
    }
#pragma unroll
    for (int cf = 0; cf < 4; ++cf) {
        int col = cf * 16 + lr;
#pragma unroll
        for (int kc = 0; kc < 4; ++kc) {
            int slot = kc * 4 + lk;
            half8 bF = *reinterpret_cast<const half8*>(&sW2[col * 128 + ((slot ^ (col & 7)) << 3)]);
            acc2[0][cf] = __builtin_amdgcn_mfma_f32_16x16x32_f16(aF[0][kc], bF, acc2[0][cf], 0, 0, 0);
            acc2[1][cf] = __builtin_amdgcn_mfma_f32_16x16x32_f16(aF[1][kc], bF, acc2[1][cf], 0, 0, 0);
        }
    }

    ushort* sP = sW1;
#pragma unroll
    for (int rf = 0; rf < 2; ++rf)
#pragma unroll
        for (int cf = 0; cf < 4; ++cf)
#pragma unroll
            for (int reg = 0; reg < 4; ++reg) {
                int row = w * 32 + rf * 16 + lk * 4 + reg;
                int col = cf * 16 + lr;
                sP[row * 64 + col] = f2h(acc2[rf][cf][reg]);
            }
    __syncthreads();

#pragma unroll
    for (int i = 0; i < 4; ++i) {
        int fid = i * 256 + t;
        int row = fid >> 3, q = fid & 7;
        int gr = row0 + row;
        if (gr < M)
            reinterpret_cast<uint4*>(Ph)[(size_t)gr * 8 + q] =
                *reinterpret_cast<const uint4*>(&sP[row * 64 + q * 8]);
    }
}

// ---------------- launch ----------------

extern "C" void kernel_launch(void* const* d_in, const int* in_sizes, int n_in,
                              void* d_out, int out_size, void* d_ws, size_t ws_size,
                              hipStream_t stream) {
    const float* X = (const float*)d_in[0];
    const float* W1 = (const float*)d_in[1];
    const float* W2 = (const float*)d_in[2];
    const float* evals = (const float*)d_in[3];
    const int* erow = (const int*)d_in[4];
    const int* ecol = (const int*)d_in[5];
    float* out = (float*)d_out;

    const int N = N_NODES;
    const int E = N_EDGES;

    char* ws = (char*)d_ws;
    size_t off = 0;
    auto alloc = [&](size_t bytes) {
        size_t o = off;
        off = (off + bytes + 255) & ~(size_t)255;
        return o;
    };
    size_t o_counts = alloc((size_t)NB2 * NCHUNK * 4);
    size_t o_offnb = alloc((size_t)NB2 * NCHUNK * 4);
    size_t o_tot = alloc((size_t)NB2 * 4);
    size_t o_bbase = alloc((size_t)(NB2 + 1) * 4);
    size_t o_ep = alloc((size_t)E * 8);
    size_t o_key = alloc((size_t)E * 4);
    size_t o_val = alloc((size_t)E * 4);
    size_t o_xh = alloc((size_t)N * 64 * 4);   // Xh [N][64] uint
    size_t o_agg = alloc((size_t)N * 64 * 4);  // aggh [N][64] uint
    size_t o_p = alloc((size_t)N * 32 * 4);    // Ph [N][32] uint
    size_t o_w1h = alloc((size_t)128 * 64 * 4);
    size_t o_w2h = alloc((size_t)64 * 64 * 4);
    (void)ws_size;

    int* counts = (int*)(ws + o_counts);
    int* offnb = (int*)(ws + o_offnb);
    int* tot = (int*)(ws + o_tot);
    int* bbase = (int*)(ws + o_bbase);
    int2* ep = (int2*)(ws + o_ep);
    uint* keyOut = (uint*)(ws + o_key);
    float* valOut = (float*)(ws + o_val);
    uint* Xh = (uint*)(ws + o_xh);
    uint* aggh = (uint*)(ws + o_agg);
    uint* Ph = (uint*)(ws + o_p);
    uint* W1h = (uint*)(ws + o_w1h);
    uint* W2h = (uint*)(ws + o_w2h);

    // conversions (independent; issue first)
    const int ncvt = N * DIM_IN / 8;
    cvt_f16_kernel<<<(ncvt + 255) / 256, 256, 0, stream>>>(X, Xh, ncvt);
    cvt_f16_kernel<<<8, 256, 0, stream>>>(W1, W1h, 128 * 128 / 8);
    cvt_f16_kernel<<<4, 256, 0, stream>>>(W2, W2h, 64 * 128 / 8);

    // build: bucket counting sort + per-bucket col-group sort (no global atomics)
    chunk_hist_kernel<<<NCHUNK, 256, 0, stream>>>(erow, counts, E);
    bucket_scan_kernel<<<NB2, 512, 0, stream>>>(counts, offnb, tot);
    base_scan_kernel<<<1, 512, 0, stream>>>(tot, bbase, E);
    coarse_scatter_kernel<<<NCHUNK, 512, 0, stream>>>(erow, ecol, evals, offnb, bbase,
                                                      keyOut, valOut, E);
    colsort_kernel<<<NB2, 256, 0, stream>>>(keyOut, valOut, bbase, ep);

    // layer 1 spmm: aggh = f16(A * Xh)
    spmm1_blocked_kernel<<<NB2, 256, 0, stream>>>(ep, bbase, Xh, aggh);
    // fused MLP: Ph = f16( tanh(aggh @ W1^T) @ W2^T )
    fused_mlp_kernel<<<NB2, 256, 0, stream>>>(aggh, W1h, W2h, Ph, N);
    // layer 2 spmm + tanh: out = tanh(A * Ph)
    spmm2_blocked_kernel<<<NB2, 256, 0, stream>>>(ep, bbase, (const ushort*)Ph, out);
}

// Round 8
// 244.633 us; speedup vs baseline: 8.6076x; 8.6076x over previous
//
#include <hip/hip_runtime.h>
#include <hip/hip_bf16.h>
#include <hip/hip_fp16.h>

#define N_NODES 100000
#define N_EDGES 1600000
#define DIM_IN 128
#define DIM_OUT 64

#define NB 391      // coarse buckets: row >> 8 (256 rows each; last has 160)
#define NCHUNK 391  // edge chunks
#define CHUNK 4096  // edges per chunk (NCHUNK*CHUNK >= N_EDGES)
#define BCAP 5120   // max edges per bucket (mean 4092, sd ~64)

typedef unsigned int uint;
typedef unsigned short ushort;
typedef _Float16 half8 __attribute__((ext_vector_type(8)));
typedef float f32x4 __attribute__((ext_vector_type(4)));

__device__ inline ushort f2h(float f) {
    __half h = __float2half(f);  // round-to-nearest-even
    return *reinterpret_cast<ushort*>(&h);
}

// ---------------- CSR build: deterministic two-level counting sort ----------------
// (round-5/6 known-good version: bucket = row>>8, fine sort by row&255 -> CSR)

__global__ __launch_bounds__(256) void chunk_hist_kernel(const int* __restrict__ erow,
                                                         int* __restrict__ counts, int E) {
    __shared__ int hist[NB];
    const int t = threadIdx.x, c = blockIdx.x;
    for (int b = t; b < NB; b += 256) hist[b] = 0;
    __syncthreads();
    const int eb = c * CHUNK;
#pragma unroll
    for (int i = 0; i < CHUNK / 256; ++i) {
        int e = eb + i * 256 + t;
        if (e < E) atomicAdd(&hist[erow[e] >> 8], 1);
    }
    __syncthreads();
    for (int b = t; b < NB; b += 256) counts[b * NCHUNK + c] = hist[b];
}

__global__ __launch_bounds__(512) void bucket_scan_kernel(const int* __restrict__ counts,
                                                          int* __restrict__ offnb,
                                                          int* __restrict__ tot) {
    __shared__ int s[512];
    const int b = blockIdx.x, t = threadIdx.x;
    int v = (t < NCHUNK) ? counts[b * NCHUNK + t] : 0;
    s[t] = v;
    __syncthreads();
#pragma unroll
    for (int o = 1; o < 512; o <<= 1) {
        int x = s[t];
        int y = (t >= o) ? s[t - o] : 0;
        __syncthreads();
        s[t] = x + y;
        __syncthreads();
    }
    if (t < NCHUNK) offnb[b * NCHUNK + t] = s[t] - v;
    if (t == 511) tot[b] = s[511];
}

__global__ __launch_bounds__(512) void base_scan_kernel(const int* __restrict__ tot,
                                                        int* __restrict__ bbase) {
    __shared__ int s[512];
    const int t = threadIdx.x;
    int v = (t < NB) ? tot[t] : 0;
    s[t] = v;
    __syncthreads();
#pragma unroll
    for (int o = 1; o < 512; o <<= 1) {
        int x = s[t];
        int y = (t >= o) ? s[t - o] : 0;
        __syncthreads();
        s[t] = x + y;
        __syncthreads();
    }
    if (t < NB) bbase[t] = s[t] - v;
    if (t == 511) bbase[NB] = s[511];
}

__global__ __launch_bounds__(512) void coarse_scatter_kernel(const int* __restrict__ erow,
                                                             const int* __restrict__ ecol,
                                                             const float* __restrict__ eval,
                                                             const int* __restrict__ offnb,
                                                             const int* __restrict__ bbase,
                                                             uint* __restrict__ keyOut,
                                                             float* __restrict__ valOut, int E) {
    __shared__ int hist[NB];
    __shared__ int segOff[NB];
    __shared__ int localOff[NB];
    __shared__ int sc[512];
    __shared__ int idxL[CHUNK];
    __shared__ int gaddrL[CHUNK];

    const int t = threadIdx.x, c = blockIdx.x;
    for (int b = t; b < NB; b += 512) {
        hist[b] = 0;
        segOff[b] = bbase[b] + offnb[b * NCHUNK + c];
    }
    __syncthreads();
    const int eb = c * CHUNK;
    uint bq[CHUNK / 512];
#pragma unroll
    for (int i = 0; i < CHUNK / 512; ++i) {
        int e = eb + i * 512 + t;
        if (e < E) {
            int b = erow[e] >> 8;
            int q = atomicAdd(&hist[b], 1);
            bq[i] = ((uint)b << 16) | (uint)q;
        } else {
            bq[i] = 0xFFFFFFFFu;
        }
    }
    __syncthreads();
    int v = (t < NB) ? hist[t] : 0;
    sc[t] = v;
    __syncthreads();
#pragma unroll
    for (int o = 1; o < 512; o <<= 1) {
        int x = sc[t];
        int y = (t >= o) ? sc[t - o] : 0;
        __syncthreads();
        sc[t] = x + y;
        __syncthreads();
    }
    if (t < NB) localOff[t] = sc[t] - v;
    __syncthreads();
#pragma unroll
    for (int i = 0; i < CHUNK / 512; ++i) {
        if (bq[i] != 0xFFFFFFFFu) {
            int b = bq[i] >> 16;
            int q = bq[i] & 0xFFFF;
            int s = localOff[b] + q;
            idxL[s] = eb + i * 512 + t;
            gaddrL[s] = segOff[b] + q;
        }
    }
    __syncthreads();
    const int m = min(CHUNK, E - eb);
    for (int s = t; s < m; s += 512) {
        int e = idxL[s];
        int g = gaddrL[s];
        keyOut[g] = ((uint)(erow[e] & 255) << 17) | (uint)ecol[e];
        valOut[g] = eval[e];
    }
}

__global__ __launch_bounds__(256) void fine_sort_kernel(const uint* __restrict__ keyOut,
                                                        const float* __restrict__ valOut,
                                                        const int* __restrict__ bbase,
                                                        int* __restrict__ row_ptr,
                                                        int2* __restrict__ ep) {
    __shared__ uint keyL[BCAP];
    __shared__ int hist[256];
    __shared__ int offs[256];
    const int b = blockIdx.x, t = threadIdx.x;
    const int s0 = bbase[b], s1 = bbase[b + 1];
    const int m = min(s1 - s0, BCAP);
    hist[t] = 0;
    __syncthreads();
    for (int j = t; j < m; j += 256) {
        uint k = keyOut[s0 + j];
        keyL[j] = k;
        atomicAdd(&hist[k >> 17], 1);
    }
    __syncthreads();
    int v = hist[t];
    offs[t] = v;
    __syncthreads();
#pragma unroll
    for (int o = 1; o < 256; o <<= 1) {
        int x = offs[t];
        int y = (t >= o) ? offs[t - o] : 0;
        __syncthreads();
        offs[t] = x + y;
        __syncthreads();
    }
    int excl = offs[t] - v;
    int row = b * 256 + t;
    if (row < N_NODES) row_ptr[row] = s0 + excl;
    if (b == NB - 1 && t == 0) row_ptr[N_NODES] = s1;
    hist[t] = excl;
    __syncthreads();
    for (int j = t; j < m; j += 256) {
        uint k = keyL[j];
        int pos = atomicAdd(&hist[k >> 17], 1);
        float vv = valOut[s0 + j];
        ep[s0 + pos] = make_int2((int)(k & 0x1FFFFu), __float_as_int(vv));
    }
}

// ---------------- f32 -> f16 conversion (weights) ----------------

__global__ __launch_bounds__(256) void cvt_f16_kernel(const float* __restrict__ in,
                                                      uint* __restrict__ outp, int n8) {
    int i = blockIdx.x * 256 + threadIdx.x;
    if (i >= n8) return;
    const float4* in4 = reinterpret_cast<const float4*>(in) + (size_t)i * 2;
    float4 a = in4[0];
    float4 b = in4[1];
    uint4 o;
    o.x = (uint)f2h(a.x) | ((uint)f2h(a.y) << 16);
    o.y = (uint)f2h(a.z) | ((uint)f2h(a.w) << 16);
    o.z = (uint)f2h(b.x) | ((uint)f2h(b.y) << 16);
    o.w = (uint)f2h(b.z) | ((uint)f2h(b.w) << 16);
    reinterpret_cast<uint4*>(outp)[i] = o;
}

// ---------------- MFMA GEMM: Out = (tanh?)(A @ W^T), K=128, f16 in/out ----------------
// 128 rows/block, 256 threads = 4 waves; wave w owns rows w*32..+31.
// LDS rows: 128 f16 = 16 x 16B slots, slot ^= (row&7) swizzle (conflict-free b128 reads).
// A is f32 [M,128] (converted during staging) or packed f16 [M,64 uint].
// W is packed f16 [NOUT,64 uint]. Out is packed f16 [M, NOUT/2 uint].

template <int NOUT, bool TANH, bool AF32>
__global__ __launch_bounds__(256) void mfma_gemm_kernel(const void* __restrict__ Ain,
                                                        const uint* __restrict__ Wh,
                                                        uint* __restrict__ Out, int M) {
    constexpr int CF = NOUT / 16;  // 8 or 4
    __shared__ __align__(16) ushort sA[128 * 128];  // A tile, then Out tile
    __shared__ __align__(16) ushort sB[NOUT * 128];

    const int t = threadIdx.x;
    const int l = t & 63;
    const int w = t >> 6;
    const int row0 = blockIdx.x * 128;
    const int lr = l & 15;
    const int lk = l >> 4;

    // stage A
    if (AF32) {
        const float* Af = (const float*)Ain;
#pragma unroll
        for (int i = 0; i < 16; ++i) {
            int fid = i * 256 + t;
            int row = fid >> 5, q4 = fid & 31;  // q4: float4 index within row
            int gr = row0 + row;
            float4 v = make_float4(0.f, 0.f, 0.f, 0.f);
            if (gr < M) v = *reinterpret_cast<const float4*>(Af + (size_t)gr * 128 + q4 * 4);
            uint2 p;
            p.x = (uint)f2h(v.x) | ((uint)f2h(v.y) << 16);
            p.y = (uint)f2h(v.z) | ((uint)f2h(v.w) << 16);
            int slot = q4 >> 1;
            *reinterpret_cast<uint2*>(&sA[row * 128 + ((slot ^ (row & 7)) << 3) + (q4 & 1) * 4]) = p;
        }
    } else {
        const uint4* A4 = (const uint4*)Ain;
#pragma unroll
        for (int i = 0; i < 8; ++i) {
            int fid = i * 256 + t;
            int row = fid >> 4, slot = fid & 15;
            int gr = row0 + row;
            uint4 v = make_uint4(0, 0, 0, 0);
            if (gr < M) v = A4[(size_t)gr * 16 + slot];
            *reinterpret_cast<uint4*>(&sA[row * 128 + ((slot ^ (row & 7)) << 3)]) = v;
        }
    }
    // stage W
#pragma unroll
    for (int i = 0; i < NOUT / 16; ++i) {
        int fid = i * 256 + t;
        int row = fid >> 4, slot = fid & 15;
        uint4 v = reinterpret_cast<const uint4*>(Wh)[row * 16 + slot];
        *reinterpret_cast<uint4*>(&sB[row * 128 + ((slot ^ (row & 7)) << 3)]) = v;
    }
    __syncthreads();

    f32x4 acc[2][CF];
#pragma unroll
    for (int rf = 0; rf < 2; ++rf)
#pragma unroll
        for (int cf = 0; cf < CF; ++cf) acc[rf][cf] = (f32x4){0.f, 0.f, 0.f, 0.f};

    half8 aF[2][4];
#pragma unroll
    for (int rf = 0; rf < 2; ++rf) {
        int row = w * 32 + rf * 16 + lr;
#pragma unroll
        for (int kc = 0; kc < 4; ++kc) {
            int slot = kc * 4 + lk;
            aF[rf][kc] = *reinterpret_cast<const half8*>(&sA[row * 128 + ((slot ^ (row & 7)) << 3)]);
        }
    }
#pragma unroll
    for (int cf = 0; cf < CF; ++cf) {
        int col = cf * 16 + lr;
#pragma unroll
        for (int kc = 0; kc < 4; ++kc) {
            int slot = kc * 4 + lk;
            half8 bF = *reinterpret_cast<const half8*>(&sB[col * 128 + ((slot ^ (col & 7)) << 3)]);
            acc[0][cf] = __builtin_amdgcn_mfma_f32_16x16x32_f16(aF[0][kc], bF, acc[0][cf], 0, 0, 0);
            acc[1][cf] = __builtin_amdgcn_mfma_f32_16x16x32_f16(aF[1][kc], bF, acc[1][cf], 0, 0, 0);
        }
    }
    __syncthreads();  // all aF loaded; sA free for reuse

    // epilogue: (tanh) + pack f16 row-major into sA region, then coalesced copy-out
    ushort* sOut = sA;  // [128][NOUT]
#pragma unroll
    for (int rf = 0; rf < 2; ++rf)
#pragma unroll
        for (int cf = 0; cf < CF; ++cf)
#pragma unroll
            for (int reg = 0; reg < 4; ++reg) {
                int row = w * 32 + rf * 16 + lk * 4 + reg;
                int col = cf * 16 + lr;
                float x = acc[rf][cf][reg];
                sOut[row * NOUT + col] = f2h(TANH ? tanhf(x) : x);
            }
    __syncthreads();
    constexpr int QPR = NOUT / 8;  // uint4 chunks per row
#pragma unroll
    for (int i = 0; i < 128 * QPR / 256; ++i) {
        int fid = i * 256 + t;
        int row = fid / QPR, q = fid % QPR;
        int gr = row0 + row;
        if (gr < M)
            reinterpret_cast<uint4*>(Out)[(size_t)gr * QPR + q] =
                *reinterpret_cast<const uint4*>(&sOut[row * NOUT + q * 8]);
    }
}

// ---------------- SpMM 128-dim f16 gather + tanh -> packed f16 H ----------------
// One wave per row; masked full-width batches (8 gathers always in flight).

__global__ __launch_bounds__(256) void spmm1_kernel(const int2* __restrict__ ep,
                                                    const int* __restrict__ row_ptr,
                                                    const uint* __restrict__ T,
                                                    uint* __restrict__ Hh) {
    int wave = threadIdx.x >> 6;
    int lane = threadIdx.x & 63;
    int r = blockIdx.x * 4 + wave;
    if (r >= N_NODES) return;
    int beg = row_ptr[r];
    int end = row_ptr[r + 1];
    if (beg >= end) {
        Hh[(size_t)r * 64 + lane] = 0u;  // tanh(0)=0
        return;
    }
    float a0x = 0.f, a0y = 0.f, a1x = 0.f, a1y = 0.f;
    for (int e = beg; e < end; e += 8) {
        int2 cv[8];
        uint xu[8];
#pragma unroll
        for (int i = 0; i < 8; ++i) {
            int idx = (e + i < end) ? e + i : end - 1;
            cv[i] = ep[idx];
        }
#pragma unroll
        for (int i = 0; i < 8; ++i) xu[i] = T[(size_t)cv[i].x * 64 + lane];
#pragma unroll
        for (int i = 0; i < 8; ++i) {
            float v = (e + i < end) ? __int_as_float(cv[i].y) : 0.f;
            __half2 h2 = *reinterpret_cast<__half2*>(&xu[i]);
            float2 f = __half22float2(h2);
            if (i & 1) { a1x += v * f.x; a1y += v * f.y; }
            else       { a0x += v * f.x; a0y += v * f.y; }
        }
    }
    Hh[(size_t)r * 64 + lane] =
        (uint)f2h(tanhf(a0x + a1x)) | ((uint)f2h(tanhf(a0y + a1y)) << 16);
}

// ---------------- SpMM 64-dim f16 gather + tanh -> f32 out ----------------

__global__ __launch_bounds__(256) void spmm2_kernel(const int2* __restrict__ ep,
                                                    const int* __restrict__ row_ptr,
                                                    const ushort* __restrict__ Ph,
                                                    float* __restrict__ out) {
    int wave = threadIdx.x >> 6;
    int lane = threadIdx.x & 63;
    int r = blockIdx.x * 4 + wave;
    if (r >= N_NODES) return;
    int beg = row_ptr[r];
    int end = row_ptr[r + 1];
    if (beg >= end) {
        out[(size_t)r * DIM_OUT + lane] = 0.f;
        return;
    }
    float acc0 = 0.f, acc1 = 0.f;
    for (int e = beg; e < end; e += 8) {
        int2 cv[8];
        ushort xu[8];
#pragma unroll
        for (int i = 0; i < 8; ++i) {
            int idx = (e + i < end) ? e + i : end - 1;
            cv[i] = ep[idx];
        }
#pragma unroll
        for (int i = 0; i < 8; ++i) xu[i] = Ph[(size_t)cv[i].x * 64 + lane];
#pragma unroll
        for (int i = 0; i < 8; ++i) {
            float v = (e + i < end) ? __int_as_float(cv[i].y) : 0.f;
            __half h = *reinterpret_cast<__half*>(&xu[i]);
            float x = __half2float(h);
            if (i & 1) acc1 += v * x;
            else       acc0 += v * x;
        }
    }
    out[(size_t)r * DIM_OUT + lane] = tanhf(acc0 + acc1);
}

// ---------------- launch ----------------

extern "C" void kernel_launch(void* const* d_in, const int* in_sizes, int n_in,
                              void* d_out, int out_size, void* d_ws, size_t ws_size,
                              hipStream_t stream) {
    const float* X = (const float*)d_in[0];
    const float* W1 = (const float*)d_in[1];
    const float* W2 = (const float*)d_in[2];
    const float* evals = (const float*)d_in[3];
    const int* erow = (const int*)d_in[4];
    const int* ecol = (const int*)d_in[5];
    float* out = (float*)d_out;

    const int N = N_NODES;
    const int E = N_EDGES;

    char* ws = (char*)d_ws;
    size_t off = 0;
    auto alloc = [&](size_t bytes) {
        size_t o = off;
        off = (off + bytes + 255) & ~(size_t)255;
        return o;
    };
    size_t o_counts = alloc((size_t)NB * NCHUNK * 4);
    size_t o_offnb = alloc((size_t)NB * NCHUNK * 4);
    size_t o_tot = alloc((size_t)NB * 4);
    size_t o_bbase = alloc((size_t)(NB + 1) * 4);
    size_t o_rowptr = alloc((size_t)(N + 1) * 4);
    size_t o_ep = alloc((size_t)E * 8);
    size_t o_key = alloc((size_t)E * 4);
    size_t o_val = alloc((size_t)E * 4);
    size_t o_xw1 = alloc((size_t)N * 64 * 4);  // XW1h [N,128] f16
    size_t o_hh = alloc((size_t)N * 64 * 4);   // Hh   [N,128] f16
    size_t o_ph = alloc((size_t)N * 32 * 4);   // Ph   [N,64]  f16
    size_t o_w1h = alloc((size_t)128 * 64 * 4);
    size_t o_w2h = alloc((size_t)64 * 64 * 4);
    (void)ws_size;

    int* counts = (int*)(ws + o_counts);
    int* offnb = (int*)(ws + o_offnb);
    int* tot = (int*)(ws + o_tot);
    int* bbase = (int*)(ws + o_bbase);
    int* row_ptr = (int*)(ws + o_rowptr);
    int2* ep = (int2*)(ws + o_ep);
    uint* keyOut = (uint*)(ws + o_key);
    float* valOut = (float*)(ws + o_val);
    uint* XW1h = (uint*)(ws + o_xw1);
    uint* Hh = (uint*)(ws + o_hh);
    uint* Ph = (uint*)(ws + o_ph);
    uint* W1h = (uint*)(ws + o_w1h);
    uint* W2h = (uint*)(ws + o_w2h);

    const int gemm_grid = (N + 127) / 128;  // 782
    const int spmm_grid = (N + 3) / 4;

    // weight conversions + XW1 = f16(X @ W1^T) (replaces cvt of X)
    cvt_f16_kernel<<<8, 256, 0, stream>>>(W1, W1h, 128 * 128 / 8);
    cvt_f16_kernel<<<4, 256, 0, stream>>>(W2, W2h, 64 * 128 / 8);
    mfma_gemm_kernel<128, false, true><<<gemm_grid, 256, 0, stream>>>(X, W1h, XW1h, N);

    // CSR build (deterministic counting sort, no global atomics)
    chunk_hist_kernel<<<NCHUNK, 256, 0, stream>>>(erow, counts, E);
    bucket_scan_kernel<<<NB, 512, 0, stream>>>(counts, offnb, tot);
    base_scan_kernel<<<1, 512, 0, stream>>>(tot, bbase);
    coarse_scatter_kernel<<<NCHUNK, 512, 0, stream>>>(erow, ecol, evals, offnb, bbase,
                                                      keyOut, valOut, E);
    fine_sort_kernel<<<NB, 256, 0, stream>>>(keyOut, valOut, bbase, row_ptr, ep);

    // H = tanh(SpMM(A, XW1))  [fused tanh epilogue]
    spmm1_kernel<<<spmm_grid, 256, 0, stream>>>(ep, row_ptr, XW1h, Hh);
    // P = f16(H @ W2^T)
    mfma_gemm_kernel<64, false, false><<<gemm_grid, 256, 0, stream>>>(Hh, W2h, Ph, N);
    // out = tanh(SpMM(A, P))
    spmm2_kernel<<<spmm_grid, 256, 0, stream>>>(ep, row_ptr, (const ushort*)Ph, out);
}

// Round 9
// 236.110 us; speedup vs baseline: 8.9183x; 1.0361x over previous
//
#include <hip/hip_runtime.h>
#include <hip/hip_bf16.h>
#include <hip/hip_fp16.h>

#define N_NODES 100000
#define N_EDGES 1600000
#define DIM_IN 128
#define DIM_OUT 64

#define NB 391      // coarse buckets: row >> 8 (256 rows each; last has 160)
#define NCHUNK 391  // edge chunks
#define CHUNK 4096  // edges per chunk (NCHUNK*CHUNK >= N_EDGES)
#define BCAP 5120   // max edges per bucket (mean 4092, sd ~64)
#define CGBITS 12   // col-group = col >> 12 (4096 cols = 1MB of 128-dim f16 table)
#define NCG 25      // ceil(100000 / 4096)
#define FBINS (256 * NCG)  // 6400 fine-sort bins

typedef unsigned int uint;
typedef unsigned short ushort;
typedef _Float16 half8 __attribute__((ext_vector_type(8)));
typedef float f32x4 __attribute__((ext_vector_type(4)));

__device__ inline ushort f2h(float f) {
    __half h = __float2half(f);  // round-to-nearest-even
    return *reinterpret_cast<ushort*>(&h);
}

// ---------------- CSR build: two-level counting sort; fine key = (row, col>>12) ----------

__global__ __launch_bounds__(256) void chunk_hist_kernel(const int* __restrict__ erow,
                                                         int* __restrict__ counts, int E) {
    __shared__ int hist[NB];
    const int t = threadIdx.x, c = blockIdx.x;
    for (int b = t; b < NB; b += 256) hist[b] = 0;
    __syncthreads();
    const int eb = c * CHUNK;
#pragma unroll
    for (int i = 0; i < CHUNK / 256; ++i) {
        int e = eb + i * 256 + t;
        if (e < E) atomicAdd(&hist[erow[e] >> 8], 1);
    }
    __syncthreads();
    for (int b = t; b < NB; b += 256) counts[b * NCHUNK + c] = hist[b];
}

__global__ __launch_bounds__(512) void bucket_scan_kernel(const int* __restrict__ counts,
                                                          int* __restrict__ offnb,
                                                          int* __restrict__ tot) {
    __shared__ int s[512];
    const int b = blockIdx.x, t = threadIdx.x;
    int v = (t < NCHUNK) ? counts[b * NCHUNK + t] : 0;
    s[t] = v;
    __syncthreads();
#pragma unroll
    for (int o = 1; o < 512; o <<= 1) {
        int x = s[t];
        int y = (t >= o) ? s[t - o] : 0;
        __syncthreads();
        s[t] = x + y;
        __syncthreads();
    }
    if (t < NCHUNK) offnb[b * NCHUNK + t] = s[t] - v;
    if (t == 511) tot[b] = s[511];
}

__global__ __launch_bounds__(512) void base_scan_kernel(const int* __restrict__ tot,
                                                        int* __restrict__ bbase) {
    __shared__ int s[512];
    const int t = threadIdx.x;
    int v = (t < NB) ? tot[t] : 0;
    s[t] = v;
    __syncthreads();
#pragma unroll
    for (int o = 1; o < 512; o <<= 1) {
        int x = s[t];
        int y = (t >= o) ? s[t - o] : 0;
        __syncthreads();
        s[t] = x + y;
        __syncthreads();
    }
    if (t < NB) bbase[t] = s[t] - v;
    if (t == 511) bbase[NB] = s[511];
}

__global__ __launch_bounds__(512) void coarse_scatter_kernel(const int* __restrict__ erow,
                                                             const int* __restrict__ ecol,
                                                             const float* __restrict__ eval,
                                                             const int* __restrict__ offnb,
                                                             const int* __restrict__ bbase,
                                                             uint* __restrict__ keyOut,
                                                             float* __restrict__ valOut, int E) {
    __shared__ int hist[NB];
    __shared__ int segOff[NB];
    __shared__ int localOff[NB];
    __shared__ int sc[512];
    __shared__ int idxL[CHUNK];
    __shared__ int gaddrL[CHUNK];

    const int t = threadIdx.x, c = blockIdx.x;
    for (int b = t; b < NB; b += 512) {
        hist[b] = 0;
        segOff[b] = bbase[b] + offnb[b * NCHUNK + c];
    }
    __syncthreads();
    const int eb = c * CHUNK;
    uint bq[CHUNK / 512];
#pragma unroll
    for (int i = 0; i < CHUNK / 512; ++i) {
        int e = eb + i * 512 + t;
        if (e < E) {
            int b = erow[e] >> 8;
            int q = atomicAdd(&hist[b], 1);
            bq[i] = ((uint)b << 16) | (uint)q;
        } else {
            bq[i] = 0xFFFFFFFFu;
        }
    }
    __syncthreads();
    int v = (t < NB) ? hist[t] : 0;
    sc[t] = v;
    __syncthreads();
#pragma unroll
    for (int o = 1; o < 512; o <<= 1) {
        int x = sc[t];
        int y = (t >= o) ? sc[t - o] : 0;
        __syncthreads();
        sc[t] = x + y;
        __syncthreads();
    }
    if (t < NB) localOff[t] = sc[t] - v;
    __syncthreads();
#pragma unroll
    for (int i = 0; i < CHUNK / 512; ++i) {
        if (bq[i] != 0xFFFFFFFFu) {
            int b = bq[i] >> 16;
            int q = bq[i] & 0xFFFF;
            int s = localOff[b] + q;
            idxL[s] = eb + i * 512 + t;
            gaddrL[s] = segOff[b] + q;
        }
    }
    __syncthreads();
    const int m = min(CHUNK, E - eb);
    for (int s = t; s < m; s += 512) {
        int e = idxL[s];
        int g = gaddrL[s];
        keyOut[g] = ((uint)(erow[e] & 255) << 17) | (uint)ecol[e];
        valOut[g] = eval[e];
    }
}

// Fine sort: 6400-bin counting sort by (row&255)*25 + (col>>12).
// Gives row-contiguous CSR with edges column-clustered (4096-col groups) within each row.
__global__ __launch_bounds__(256) void fine_sort_kernel(const uint* __restrict__ keyOut,
                                                        const float* __restrict__ valOut,
                                                        const int* __restrict__ bbase,
                                                        int* __restrict__ row_ptr,
                                                        int2* __restrict__ ep) {
    __shared__ uint keyL[BCAP];   // 20 KB
    __shared__ int hist[FBINS];   // 25.6 KB
    __shared__ int tsum[256];
    const int b = blockIdx.x, t = threadIdx.x;
    const int s0 = bbase[b], s1 = bbase[b + 1];
    const int m = min(s1 - s0, BCAP);
    for (int i = t; i < FBINS; i += 256) hist[i] = 0;
    __syncthreads();
    for (int j = t; j < m; j += 256) {
        uint k = keyOut[s0 + j];
        keyL[j] = k;
        int bin = (int)(k >> 17) * NCG + (int)((k & 0x1FFFFu) >> CGBITS);
        atomicAdd(&hist[bin], 1);
    }
    __syncthreads();
    // thread t owns bins [t*NCG, (t+1)*NCG) == row-local t's bins
    int loc[NCG];
    int run = 0;
#pragma unroll
    for (int i = 0; i < NCG; ++i) {
        loc[i] = run;
        run += hist[t * NCG + i];
    }
    tsum[t] = run;
    __syncthreads();
#pragma unroll
    for (int o = 1; o < 256; o <<= 1) {
        int x = tsum[t];
        int y = (t >= o) ? tsum[t - o] : 0;
        __syncthreads();
        tsum[t] = x + y;
        __syncthreads();
    }
    int excl = tsum[t] - run;  // exclusive start of row-local t
    // row_ptr for this row
    int row = b * 256 + t;
    if (row < N_NODES) row_ptr[row] = s0 + excl;
    if (b == NB - 1 && t == 0) row_ptr[N_NODES] = s1;
#pragma unroll
    for (int i = 0; i < NCG; ++i) hist[t * NCG + i] = excl + loc[i];
    __syncthreads();
    for (int j = t; j < m; j += 256) {
        uint k = keyL[j];
        int bin = (int)(k >> 17) * NCG + (int)((k & 0x1FFFFu) >> CGBITS);
        int pos = atomicAdd(&hist[bin], 1);
        ep[s0 + pos] = make_int2((int)(k & 0x1FFFFu), __float_as_int(valOut[s0 + j]));
    }
}

// ---------------- f32 -> f16 conversion (weights) ----------------

__global__ __launch_bounds__(256) void cvt_f16_kernel(const float* __restrict__ in,
                                                      uint* __restrict__ outp, int n8) {
    int i = blockIdx.x * 256 + threadIdx.x;
    if (i >= n8) return;
    const float4* in4 = reinterpret_cast<const float4*>(in) + (size_t)i * 2;
    float4 a = in4[0];
    float4 b = in4[1];
    uint4 o;
    o.x = (uint)f2h(a.x) | ((uint)f2h(a.y) << 16);
    o.y = (uint)f2h(a.z) | ((uint)f2h(a.w) << 16);
    o.z = (uint)f2h(b.x) | ((uint)f2h(b.y) << 16);
    o.w = (uint)f2h(b.z) | ((uint)f2h(b.w) << 16);
    reinterpret_cast<uint4*>(outp)[i] = o;
}

// ---------------- MFMA GEMM: Out = (tanh?)(A @ W^T), K=128, f16 in/out ----------------

template <int NOUT, bool TANH, bool AF32>
__global__ __launch_bounds__(256) void mfma_gemm_kernel(const void* __restrict__ Ain,
                                                        const uint* __restrict__ Wh,
                                                        uint* __restrict__ Out, int M) {
    constexpr int CF = NOUT / 16;  // 8 or 4
    __shared__ __align__(16) ushort sA[128 * 128];  // A tile, then Out tile
    __shared__ __align__(16) ushort sB[NOUT * 128];

    const int t = threadIdx.x;
    const int l = t & 63;
    const int w = t >> 6;
    const int row0 = blockIdx.x * 128;
    const int lr = l & 15;
    const int lk = l >> 4;

    if (AF32) {
        const float* Af = (const float*)Ain;
#pragma unroll
        for (int i = 0; i < 16; ++i) {
            int fid = i * 256 + t;
            int row = fid >> 5, q4 = fid & 31;
            int gr = row0 + row;
            float4 v = make_float4(0.f, 0.f, 0.f, 0.f);
            if (gr < M) v = *reinterpret_cast<const float4*>(Af + (size_t)gr * 128 + q4 * 4);
            uint2 p;
            p.x = (uint)f2h(v.x) | ((uint)f2h(v.y) << 16);
            p.y = (uint)f2h(v.z) | ((uint)f2h(v.w) << 16);
            int slot = q4 >> 1;
            *reinterpret_cast<uint2*>(&sA[row * 128 + ((slot ^ (row & 7)) << 3) + (q4 & 1) * 4]) = p;
        }
    } else {
        const uint4* A4 = (const uint4*)Ain;
#pragma unroll
        for (int i = 0; i < 8; ++i) {
            int fid = i * 256 + t;
            int row = fid >> 4, slot = fid & 15;
            int gr = row0 + row;
            uint4 v = make_uint4(0, 0, 0, 0);
            if (gr < M) v = A4[(size_t)gr * 16 + slot];
            *reinterpret_cast<uint4*>(&sA[row * 128 + ((slot ^ (row & 7)) << 3)]) = v;
        }
    }
#pragma unroll
    for (int i = 0; i < NOUT / 16; ++i) {
        int fid = i * 256 + t;
        int row = fid >> 4, slot = fid & 15;
        uint4 v = reinterpret_cast<const uint4*>(Wh)[row * 16 + slot];
        *reinterpret_cast<uint4*>(&sB[row * 128 + ((slot ^ (row & 7)) << 3)]) = v;
    }
    __syncthreads();

    f32x4 acc[2][CF];
#pragma unroll
    for (int rf = 0; rf < 2; ++rf)
#pragma unroll
        for (int cf = 0; cf < CF; ++cf) acc[rf][cf] = (f32x4){0.f, 0.f, 0.f, 0.f};

    half8 aF[2][4];
#pragma unroll
    for (int rf = 0; rf < 2; ++rf) {
        int row = w * 32 + rf * 16 + lr;
#pragma unroll
        for (int kc = 0; kc < 4; ++kc) {
            int slot = kc * 4 + lk;
            aF[rf][kc] = *reinterpret_cast<const half8*>(&sA[row * 128 + ((slot ^ (row & 7)) << 3)]);
        }
    }
#pragma unroll
    for (int cf = 0; cf < CF; ++cf) {
        int col = cf * 16 + lr;
#pragma unroll
        for (int kc = 0; kc < 4; ++kc) {
            int slot = kc * 4 + lk;
            half8 bF = *reinterpret_cast<const half8*>(&sB[col * 128 + ((slot ^ (col & 7)) << 3)]);
            acc[0][cf] = __builtin_amdgcn_mfma_f32_16x16x32_f16(aF[0][kc], bF, acc[0][cf], 0, 0, 0);
            acc[1][cf] = __builtin_amdgcn_mfma_f32_16x16x32_f16(aF[1][kc], bF, acc[1][cf], 0, 0, 0);
        }
    }
    __syncthreads();

    ushort* sOut = sA;
#pragma unroll
    for (int rf = 0; rf < 2; ++rf)
#pragma unroll
        for (int cf = 0; cf < CF; ++cf)
#pragma unroll
            for (int reg = 0; reg < 4; ++reg) {
                int row = w * 32 + rf * 16 + lk * 4 + reg;
                int col = cf * 16 + lr;
                float x = acc[rf][cf][reg];
                sOut[row * NOUT + col] = f2h(TANH ? tanhf(x) : x);
            }
    __syncthreads();
    constexpr int QPR = NOUT / 8;
#pragma unroll
    for (int i = 0; i < 128 * QPR / 256; ++i) {
        int fid = i * 256 + t;
        int row = fid / QPR, q = fid % QPR;
        int gr = row0 + row;
        if (gr < M)
            reinterpret_cast<uint4*>(Out)[(size_t)gr * QPR + q] =
                *reinterpret_cast<const uint4*>(&sOut[row * NOUT + q * 8]);
    }
}

// ---------------- SpMM 128-dim f16 gather + tanh -> packed f16 H ----------------

__global__ __launch_bounds__(256) void spmm1_kernel(const int2* __restrict__ ep,
                                                    const int* __restrict__ row_ptr,
                                                    const uint* __restrict__ T,
                                                    uint* __restrict__ Hh) {
    int wave = threadIdx.x >> 6;
    int lane = threadIdx.x & 63;
    int r = blockIdx.x * 4 + wave;
    if (r >= N_NODES) return;
    int beg = row_ptr[r];
    int end = row_ptr[r + 1];
    float a0x = 0.f, a0y = 0.f, a1x = 0.f, a1y = 0.f;
    int e = beg;
    for (; e + 7 < end; e += 8) {
        int2 cv[8];
        uint xu[8];
#pragma unroll
        for (int i = 0; i < 8; ++i) cv[i] = ep[e + i];
#pragma unroll
        for (int i = 0; i < 8; ++i) xu[i] = T[(size_t)cv[i].x * 64 + lane];
#pragma unroll
        for (int i = 0; i < 8; ++i) {
            float v = __int_as_float(cv[i].y);
            __half2 h2 = *reinterpret_cast<__half2*>(&xu[i]);
            float2 f = __half22float2(h2);
            if (i & 1) { a1x += v * f.x; a1y += v * f.y; }
            else       { a0x += v * f.x; a0y += v * f.y; }
        }
    }
    for (; e < end; ++e) {
        int2 cv = ep[e];
        float v = __int_as_float(cv.y);
        uint xu = T[(size_t)cv.x * 64 + lane];
        __half2 h2 = *reinterpret_cast<__half2*>(&xu);
        float2 f = __half22float2(h2);
        a0x += v * f.x;
        a0y += v * f.y;
    }
    Hh[(size_t)r * 64 + lane] =
        (uint)f2h(tanhf(a0x + a1x)) | ((uint)f2h(tanhf(a0y + a1y)) << 16);
}

// ---------------- SpMM 64-dim f16 gather + tanh -> f32 out ----------------

__global__ __launch_bounds__(256) void spmm2_kernel(const int2* __restrict__ ep,
                                                    const int* __restrict__ row_ptr,
                                                    const ushort* __restrict__ Ph,
                                                    float* __restrict__ out) {
    int wave = threadIdx.x >> 6;
    int lane = threadIdx.x & 63;
    int r = blockIdx.x * 4 + wave;
    if (r >= N_NODES) return;
    int beg = row_ptr[r];
    int end = row_ptr[r + 1];
    float acc0 = 0.f, acc1 = 0.f;
    int e = beg;
    for (; e + 7 < end; e += 8) {
        int2 cv[8];
        ushort xu[8];
#pragma unroll
        for (int i = 0; i < 8; ++i) cv[i] = ep[e + i];
#pragma unroll
        for (int i = 0; i < 8; ++i) xu[i] = Ph[(size_t)cv[i].x * 64 + lane];
#pragma unroll
        for (int i = 0; i < 8; ++i) {
            float v = __int_as_float(cv[i].y);
            __half h = *reinterpret_cast<__half*>(&xu[i]);
            float x = __half2float(h);
            if (i & 1) acc1 += v * x;
            else       acc0 += v * x;
        }
    }
    for (; e < end; ++e) {
        int2 cv = ep[e];
        ushort u = Ph[(size_t)cv.x * 64 + lane];
        __half h = *reinterpret_cast<__half*>(&u);
        acc0 += __int_as_float(cv.y) * __half2float(h);
    }
    out[(size_t)r * DIM_OUT + lane] = tanhf(acc0 + acc1);
}

// ---------------- launch ----------------

extern "C" void kernel_launch(void* const* d_in, const int* in_sizes, int n_in,
                              void* d_out, int out_size, void* d_ws, size_t ws_size,
                              hipStream_t stream) {
    const float* X = (const float*)d_in[0];
    const float* W1 = (const float*)d_in[1];
    const float* W2 = (const float*)d_in[2];
    const float* evals = (const float*)d_in[3];
    const int* erow = (const int*)d_in[4];
    const int* ecol = (const int*)d_in[5];
    float* out = (float*)d_out;

    const int N = N_NODES;
    const int E = N_EDGES;

    char* ws = (char*)d_ws;
    size_t off = 0;
    auto alloc = [&](size_t bytes) {
        size_t o = off;
        off = (off + bytes + 255) & ~(size_t)255;
        return o;
    };
    size_t o_counts = alloc((size_t)NB * NCHUNK * 4);
    size_t o_offnb = alloc((size_t)NB * NCHUNK * 4);
    size_t o_tot = alloc((size_t)NB * 4);
    size_t o_bbase = alloc((size_t)(NB + 1) * 4);
    size_t o_rowptr = alloc((size_t)(N + 1) * 4);
    size_t o_ep = alloc((size_t)E * 8);
    size_t o_key = alloc((size_t)E * 4);
    size_t o_val = alloc((size_t)E * 4);
    size_t o_xw1 = alloc((size_t)N * 64 * 4);  // XW1h [N,128] f16
    size_t o_hh = alloc((size_t)N * 64 * 4);   // Hh   [N,128] f16
    size_t o_ph = alloc((size_t)N * 32 * 4);   // Ph   [N,64]  f16
    size_t o_w1h = alloc((size_t)128 * 64 * 4);
    size_t o_w2h = alloc((size_t)64 * 64 * 4);
    (void)ws_size;

    int* counts = (int*)(ws + o_counts);
    int* offnb = (int*)(ws + o_offnb);
    int* tot = (int*)(ws + o_tot);
    int* bbase = (int*)(ws + o_bbase);
    int* row_ptr = (int*)(ws + o_rowptr);
    int2* ep = (int2*)(ws + o_ep);
    uint* keyOut = (uint*)(ws + o_key);
    float* valOut = (float*)(ws + o_val);
    uint* XW1h = (uint*)(ws + o_xw1);
    uint* Hh = (uint*)(ws + o_hh);
    uint* Ph = (uint*)(ws + o_ph);
    uint* W1h = (uint*)(ws + o_w1h);
    uint* W2h = (uint*)(ws + o_w2h);

    const int gemm_grid = (N + 127) / 128;  // 782
    const int spmm_grid = (N + 3) / 4;

    // weight conversions + XW1 = f16(X @ W1^T)
    cvt_f16_kernel<<<8, 256, 0, stream>>>(W1, W1h, 128 * 128 / 8);
    cvt_f16_kernel<<<4, 256, 0, stream>>>(W2, W2h, 64 * 128 / 8);
    mfma_gemm_kernel<128, false, true><<<gemm_grid, 256, 0, stream>>>(X, W1h, XW1h, N);

    // CSR build (deterministic counting sort; within-row column clustering)
    chunk_hist_kernel<<<NCHUNK, 256, 0, stream>>>(erow, counts, E);
    bucket_scan_kernel<<<NB, 512, 0, stream>>>(counts, offnb, tot);
    base_scan_kernel<<<1, 512, 0, stream>>>(tot, bbase);
    coarse_scatter_kernel<<<NCHUNK, 512, 0, stream>>>(erow, ecol, evals, offnb, bbase,
                                                      keyOut, valOut, E);
    fine_sort_kernel<<<NB, 256, 0, stream>>>(keyOut, valOut, bbase, row_ptr, ep);

    // H = tanh(SpMM(A, XW1))
    spmm1_kernel<<<spmm_grid, 256, 0, stream>>>(ep, row_ptr, XW1h, Hh);
    // P = f16(H @ W2^T)
    mfma_gemm_kernel<64, false, false><<<gemm_grid, 256, 0, stream>>>(Hh, W2h, Ph, N);
    // out = tanh(SpMM(A, P))
    spmm2_kernel<<<spmm_grid, 256, 0, stream>>>(ep, row_ptr, (const ushort*)Ph, out);
}

// Round 10
// 208.086 us; speedup vs baseline: 10.1194x; 1.1347x over previous
//
#include <hip/hip_runtime.h>
#include <hip/hip_bf16.h>
#include <hip/hip_fp16.h>

#define N_NODES 100000
#define N_EDGES 1600000
#define DIM_IN 128
#define DIM_OUT 64

#define NB 391      // coarse buckets: row >> 8 (256 rows each; last has 160)
#define NCHUNK 391  // edge chunks
#define CHUNK 4096  // edges per chunk (NCHUNK*CHUNK >= N_EDGES)
#define BCAP 5120   // max edges per bucket (mean 4092, sd ~64)
#define EPCAP 6144  // fixed ep region per bucket (padded total mean ~4990)

typedef unsigned int uint;
typedef unsigned short ushort;
typedef _Float16 half8 __attribute__((ext_vector_type(8)));
typedef float f32x4 __attribute__((ext_vector_type(4)));

__device__ inline ushort f2h(float f) {
    __half h = __float2half(f);  // round-to-nearest-even
    return *reinterpret_cast<ushort*>(&h);
}

// ---------------- CSR build: two-level counting sort, 8-padded rows ----------------

__global__ __launch_bounds__(256) void chunk_hist_kernel(const int* __restrict__ erow,
                                                         int* __restrict__ counts, int E) {
    __shared__ int hist[NB];
    const int t = threadIdx.x, c = blockIdx.x;
    for (int b = t; b < NB; b += 256) hist[b] = 0;
    __syncthreads();
    const int eb = c * CHUNK;
#pragma unroll
    for (int i = 0; i < CHUNK / 256; ++i) {
        int e = eb + i * 256 + t;
        if (e < E) atomicAdd(&hist[erow[e] >> 8], 1);
    }
    __syncthreads();
    for (int b = t; b < NB; b += 256) counts[b * NCHUNK + c] = hist[b];
}

__global__ __launch_bounds__(512) void bucket_scan_kernel(const int* __restrict__ counts,
                                                          int* __restrict__ offnb,
                                                          int* __restrict__ tot) {
    __shared__ int s[512];
    const int b = blockIdx.x, t = threadIdx.x;
    int v = (t < NCHUNK) ? counts[b * NCHUNK + t] : 0;
    s[t] = v;
    __syncthreads();
#pragma unroll
    for (int o = 1; o < 512; o <<= 1) {
        int x = s[t];
        int y = (t >= o) ? s[t - o] : 0;
        __syncthreads();
        s[t] = x + y;
        __syncthreads();
    }
    if (t < NCHUNK) offnb[b * NCHUNK + t] = s[t] - v;
    if (t == 511) tot[b] = s[511];
}

__global__ __launch_bounds__(512) void base_scan_kernel(const int* __restrict__ tot,
                                                        int* __restrict__ bbase) {
    __shared__ int s[512];
    const int t = threadIdx.x;
    int v = (t < NB) ? tot[t] : 0;
    s[t] = v;
    __syncthreads();
#pragma unroll
    for (int o = 1; o < 512; o <<= 1) {
        int x = s[t];
        int y = (t >= o) ? s[t - o] : 0;
        __syncthreads();
        s[t] = x + y;
        __syncthreads();
    }
    if (t < NB) bbase[t] = s[t] - v;
    if (t == 511) bbase[NB] = s[511];
}

__global__ __launch_bounds__(512) void coarse_scatter_kernel(const int* __restrict__ erow,
                                                             const int* __restrict__ ecol,
                                                             const float* __restrict__ eval,
                                                             const int* __restrict__ offnb,
                                                             const int* __restrict__ bbase,
                                                             uint* __restrict__ keyOut,
                                                             float* __restrict__ valOut, int E) {
    __shared__ int hist[NB];
    __shared__ int segOff[NB];
    __shared__ int localOff[NB];
    __shared__ int sc[512];
    __shared__ int idxL[CHUNK];
    __shared__ int gaddrL[CHUNK];

    const int t = threadIdx.x, c = blockIdx.x;
    for (int b = t; b < NB; b += 512) {
        hist[b] = 0;
        segOff[b] = bbase[b] + offnb[b * NCHUNK + c];
    }
    __syncthreads();
    const int eb = c * CHUNK;
    uint bq[CHUNK / 512];
#pragma unroll
    for (int i = 0; i < CHUNK / 512; ++i) {
        int e = eb + i * 512 + t;
        if (e < E) {
            int b = erow[e] >> 8;
            int q = atomicAdd(&hist[b], 1);
            bq[i] = ((uint)b << 16) | (uint)q;
        } else {
            bq[i] = 0xFFFFFFFFu;
        }
    }
    __syncthreads();
    int v = (t < NB) ? hist[t] : 0;
    sc[t] = v;
    __syncthreads();
#pragma unroll
    for (int o = 1; o < 512; o <<= 1) {
        int x = sc[t];
        int y = (t >= o) ? sc[t - o] : 0;
        __syncthreads();
        sc[t] = x + y;
        __syncthreads();
    }
    if (t < NB) localOff[t] = sc[t] - v;
    __syncthreads();
#pragma unroll
    for (int i = 0; i < CHUNK / 512; ++i) {
        if (bq[i] != 0xFFFFFFFFu) {
            int b = bq[i] >> 16;
            int q = bq[i] & 0xFFFF;
            int s = localOff[b] + q;
            idxL[s] = eb + i * 512 + t;
            gaddrL[s] = segOff[b] + q;
        }
    }
    __syncthreads();
    const int m = min(CHUNK, E - eb);
    for (int s = t; s < m; s += 512) {
        int e = idxL[s];
        int g = gaddrL[s];
        keyOut[g] = ((uint)(erow[e] & 255) << 17) | (uint)ecol[e];
        valOut[g] = eval[e];
    }
}

// Fine sort: per-bucket 256-bin counting sort by row; each row's segment padded to a
// multiple of 8 with (col=0, val=0) edges so the SpMM inner loop is tail-free.
// Bucket b owns ep[b*EPCAP .. b*EPCAP+paddedTotal). row_ptr = start, row_len = padded len.
__global__ __launch_bounds__(256) void fine_sort_kernel(const uint* __restrict__ keyOut,
                                                        const float* __restrict__ valOut,
                                                        const int* __restrict__ bbase,
                                                        int* __restrict__ row_ptr,
                                                        int* __restrict__ row_len,
                                                        int2* __restrict__ ep) {
    __shared__ uint keyL[BCAP];
    __shared__ int hist[256];
    __shared__ int offs[256];
    const int b = blockIdx.x, t = threadIdx.x;
    const int s0 = bbase[b], s1 = bbase[b + 1];
    const int m = min(s1 - s0, BCAP);
    hist[t] = 0;
    __syncthreads();
    for (int j = t; j < m; j += 256) {
        uint k = keyOut[s0 + j];
        keyL[j] = k;
        atomicAdd(&hist[k >> 17], 1);
    }
    __syncthreads();
    const int deg = hist[t];
    const int pdeg = (deg + 7) & ~7;  // pad to multiple of 8
    offs[t] = pdeg;
    __syncthreads();
#pragma unroll
    for (int o = 1; o < 256; o <<= 1) {
        int x = offs[t];
        int y = (t >= o) ? offs[t - o] : 0;
        __syncthreads();
        offs[t] = x + y;
        __syncthreads();
    }
    const int pexcl = offs[t] - pdeg;
    const int base = b * EPCAP;
    const int row = b * 256 + t;
    if (row < N_NODES) {
        row_ptr[row] = base + pexcl;
        row_len[row] = pdeg;
    }
    hist[t] = pexcl;  // running placement cursor
    __syncthreads();
    for (int j = t; j < m; j += 256) {
        uint k = keyL[j];
        int pos = atomicAdd(&hist[k >> 17], 1);
        ep[base + pos] = make_int2((int)(k & 0x1FFFFu), __float_as_int(valOut[s0 + j]));
    }
    __syncthreads();
    // pad entries for this thread's row
    for (int j = pexcl + deg; j < pexcl + pdeg; ++j)
        ep[base + j] = make_int2(0, 0);
}

// ---------------- f32 -> f16 conversion (weights) ----------------

__global__ __launch_bounds__(256) void cvt_f16_kernel(const float* __restrict__ in,
                                                      uint* __restrict__ outp, int n8) {
    int i = blockIdx.x * 256 + threadIdx.x;
    if (i >= n8) return;
    const float4* in4 = reinterpret_cast<const float4*>(in) + (size_t)i * 2;
    float4 a = in4[0];
    float4 b = in4[1];
    uint4 o;
    o.x = (uint)f2h(a.x) | ((uint)f2h(a.y) << 16);
    o.y = (uint)f2h(a.z) | ((uint)f2h(a.w) << 16);
    o.z = (uint)f2h(b.x) | ((uint)f2h(b.y) << 16);
    o.w = (uint)f2h(b.z) | ((uint)f2h(b.w) << 16);
    reinterpret_cast<uint4*>(outp)[i] = o;
}

// ---------------- MFMA GEMM: Out = (tanh?)(A @ W^T), K=128, f16 in/out ----------------

template <int NOUT, bool TANH, bool AF32>
__global__ __launch_bounds__(256) void mfma_gemm_kernel(const void* __restrict__ Ain,
                                                        const uint* __restrict__ Wh,
                                                        uint* __restrict__ Out, int M) {
    constexpr int CF = NOUT / 16;  // 8 or 4
    __shared__ __align__(16) ushort sA[128 * 128];  // A tile, then Out tile
    __shared__ __align__(16) ushort sB[NOUT * 128];

    const int t = threadIdx.x;
    const int l = t & 63;
    const int w = t >> 6;
    const int row0 = blockIdx.x * 128;
    const int lr = l & 15;
    const int lk = l >> 4;

    if (AF32) {
        const float* Af = (const float*)Ain;
#pragma unroll
        for (int i = 0; i < 16; ++i) {
            int fid = i * 256 + t;
            int row = fid >> 5, q4 = fid & 31;
            int gr = row0 + row;
            float4 v = make_float4(0.f, 0.f, 0.f, 0.f);
            if (gr < M) v = *reinterpret_cast<const float4*>(Af + (size_t)gr * 128 + q4 * 4);
            uint2 p;
            p.x = (uint)f2h(v.x) | ((uint)f2h(v.y) << 16);
            p.y = (uint)f2h(v.z) | ((uint)f2h(v.w) << 16);
            int slot = q4 >> 1;
            *reinterpret_cast<uint2*>(&sA[row * 128 + ((slot ^ (row & 7)) << 3) + (q4 & 1) * 4]) = p;
        }
    } else {
        const uint4* A4 = (const uint4*)Ain;
#pragma unroll
        for (int i = 0; i < 8; ++i) {
            int fid = i * 256 + t;
            int row = fid >> 4, slot = fid & 15;
            int gr = row0 + row;
            uint4 v = make_uint4(0, 0, 0, 0);
            if (gr < M) v = A4[(size_t)gr * 16 + slot];
            *reinterpret_cast<uint4*>(&sA[row * 128 + ((slot ^ (row & 7)) << 3)]) = v;
        }
    }
#pragma unroll
    for (int i = 0; i < NOUT / 16; ++i) {
        int fid = i * 256 + t;
        int row = fid >> 4, slot = fid & 15;
        uint4 v = reinterpret_cast<const uint4*>(Wh)[row * 16 + slot];
        *reinterpret_cast<uint4*>(&sB[row * 128 + ((slot ^ (row & 7)) << 3)]) = v;
    }
    __syncthreads();

    f32x4 acc[2][CF];
#pragma unroll
    for (int rf = 0; rf < 2; ++rf)
#pragma unroll
        for (int cf = 0; cf < CF; ++cf) acc[rf][cf] = (f32x4){0.f, 0.f, 0.f, 0.f};

    half8 aF[2][4];
#pragma unroll
    for (int rf = 0; rf < 2; ++rf) {
        int row = w * 32 + rf * 16 + lr;
#pragma unroll
        for (int kc = 0; kc < 4; ++kc) {
            int slot = kc * 4 + lk;
            aF[rf][kc] = *reinterpret_cast<const half8*>(&sA[row * 128 + ((slot ^ (row & 7)) << 3)]);
        }
    }
#pragma unroll
    for (int cf = 0; cf < CF; ++cf) {
        int col = cf * 16 + lr;
#pragma unroll
        for (int kc = 0; kc < 4; ++kc) {
            int slot = kc * 4 + lk;
            half8 bF = *reinterpret_cast<const half8*>(&sB[col * 128 + ((slot ^ (col & 7)) << 3)]);
            acc[0][cf] = __builtin_amdgcn_mfma_f32_16x16x32_f16(aF[0][kc], bF, acc[0][cf], 0, 0, 0);
            acc[1][cf] = __builtin_amdgcn_mfma_f32_16x16x32_f16(aF[1][kc], bF, acc[1][cf], 0, 0, 0);
        }
    }
    __syncthreads();

    ushort* sOut = sA;
#pragma unroll
    for (int rf = 0; rf < 2; ++rf)
#pragma unroll
        for (int cf = 0; cf < CF; ++cf)
#pragma unroll
            for (int reg = 0; reg < 4; ++reg) {
                int row = w * 32 + rf * 16 + lk * 4 + reg;
                int col = cf * 16 + lr;
                float x = acc[rf][cf][reg];
                sOut[row * NOUT + col] = f2h(TANH ? tanhf(x) : x);
            }
    __syncthreads();
    constexpr int QPR = NOUT / 8;
#pragma unroll
    for (int i = 0; i < 128 * QPR / 256; ++i) {
        int fid = i * 256 + t;
        int row = fid / QPR, q = fid % QPR;
        int gr = row0 + row;
        if (gr < M)
            reinterpret_cast<uint4*>(Out)[(size_t)gr * QPR + q] =
                *reinterpret_cast<const uint4*>(&sOut[row * NOUT + q * 8]);
    }
}

// ---------------- SpMM 128-dim f16 gather + tanh -> packed f16 H (tail-free) ----------

__global__ __launch_bounds__(256) void spmm1_kernel(const int2* __restrict__ ep,
                                                    const int* __restrict__ row_ptr,
                                                    const int* __restrict__ row_len,
                                                    const uint* __restrict__ T,
                                                    uint* __restrict__ Hh) {
    int wave = threadIdx.x >> 6;
    int lane = threadIdx.x & 63;
    int r = blockIdx.x * 4 + wave;
    if (r >= N_NODES) return;
    int beg = row_ptr[r];
    int end = beg + row_len[r];
    float a0x = 0.f, a0y = 0.f, a1x = 0.f, a1y = 0.f;
    for (int e = beg; e < end; e += 8) {
        int2 cv[8];
        uint xu[8];
#pragma unroll
        for (int i = 0; i < 8; ++i) cv[i] = ep[e + i];
#pragma unroll
        for (int i = 0; i < 8; ++i) xu[i] = T[(size_t)cv[i].x * 64 + lane];
#pragma unroll
        for (int i = 0; i < 8; ++i) {
            float v = __int_as_float(cv[i].y);
            __half2 h2 = *reinterpret_cast<__half2*>(&xu[i]);
            float2 f = __half22float2(h2);
            if (i & 1) { a1x += v * f.x; a1y += v * f.y; }
            else       { a0x += v * f.x; a0y += v * f.y; }
        }
    }
    Hh[(size_t)r * 64 + lane] =
        (uint)f2h(tanhf(a0x + a1x)) | ((uint)f2h(tanhf(a0y + a1y)) << 16);
}

// ---------------- SpMM 64-dim f16 gather + tanh -> f32 out (tail-free) ----------------

__global__ __launch_bounds__(256) void spmm2_kernel(const int2* __restrict__ ep,
                                                    const int* __restrict__ row_ptr,
                                                    const int* __restrict__ row_len,
                                                    const ushort* __restrict__ Ph,
                                                    float* __restrict__ out) {
    int wave = threadIdx.x >> 6;
    int lane = threadIdx.x & 63;
    int r = blockIdx.x * 4 + wave;
    if (r >= N_NODES) return;
    int beg = row_ptr[r];
    int end = beg + row_len[r];
    float acc0 = 0.f, acc1 = 0.f;
    for (int e = beg; e < end; e += 8) {
        int2 cv[8];
        ushort xu[8];
#pragma unroll
        for (int i = 0; i < 8; ++i) cv[i] = ep[e + i];
#pragma unroll
        for (int i = 0; i < 8; ++i) xu[i] = Ph[(size_t)cv[i].x * 64 + lane];
#pragma unroll
        for (int i = 0; i < 8; ++i) {
            float v = __int_as_float(cv[i].y);
            __half h = *reinterpret_cast<__half*>(&xu[i]);
            float x = __half2float(h);
            if (i & 1) acc1 += v * x;
            else       acc0 += v * x;
        }
    }
    out[(size_t)r * DIM_OUT + lane] = tanhf(acc0 + acc1);
}

// ---------------- launch ----------------

extern "C" void kernel_launch(void* const* d_in, const int* in_sizes, int n_in,
                              void* d_out, int out_size, void* d_ws, size_t ws_size,
                              hipStream_t stream) {
    const float* X = (const float*)d_in[0];
    const float* W1 = (const float*)d_in[1];
    const float* W2 = (const float*)d_in[2];
    const float* evals = (const float*)d_in[3];
    const int* erow = (const int*)d_in[4];
    const int* ecol = (const int*)d_in[5];
    float* out = (float*)d_out;

    const int N = N_NODES;
    const int E = N_EDGES;

    char* ws = (char*)d_ws;
    size_t off = 0;
    auto alloc = [&](size_t bytes) {
        size_t o = off;
        off = (off + bytes + 255) & ~(size_t)255;
        return o;
    };
    size_t o_counts = alloc((size_t)NB * NCHUNK * 4);
    size_t o_offnb = alloc((size_t)NB * NCHUNK * 4);
    size_t o_tot = alloc((size_t)NB * 4);
    size_t o_bbase = alloc((size_t)(NB + 1) * 4);
    size_t o_rowptr = alloc((size_t)N * 4);
    size_t o_rowlen = alloc((size_t)N * 4);
    size_t o_ep = alloc((size_t)NB * EPCAP * 8);  // 19.2MB padded CSR
    size_t o_key = alloc((size_t)E * 4);
    size_t o_val = alloc((size_t)E * 4);
    size_t o_xw1 = alloc((size_t)N * 64 * 4);  // XW1h [N,128] f16
    size_t o_hh = alloc((size_t)N * 64 * 4);   // Hh   [N,128] f16
    size_t o_ph = alloc((size_t)N * 32 * 4);   // Ph   [N,64]  f16
    size_t o_w1h = alloc((size_t)128 * 64 * 4);
    size_t o_w2h = alloc((size_t)64 * 64 * 4);
    (void)ws_size;

    int* counts = (int*)(ws + o_counts);
    int* offnb = (int*)(ws + o_offnb);
    int* tot = (int*)(ws + o_tot);
    int* bbase = (int*)(ws + o_bbase);
    int* row_ptr = (int*)(ws + o_rowptr);
    int* row_len = (int*)(ws + o_rowlen);
    int2* ep = (int2*)(ws + o_ep);
    uint* keyOut = (uint*)(ws + o_key);
    float* valOut = (float*)(ws + o_val);
    uint* XW1h = (uint*)(ws + o_xw1);
    uint* Hh = (uint*)(ws + o_hh);
    uint* Ph = (uint*)(ws + o_ph);
    uint* W1h = (uint*)(ws + o_w1h);
    uint* W2h = (uint*)(ws + o_w2h);

    const int gemm_grid = (N + 127) / 128;  // 782
    const int spmm_grid = (N + 3) / 4;

    // weight conversions + XW1 = f16(X @ W1^T)
    cvt_f16_kernel<<<8, 256, 0, stream>>>(W1, W1h, 128 * 128 / 8);
    cvt_f16_kernel<<<4, 256, 0, stream>>>(W2, W2h, 64 * 128 / 8);
    mfma_gemm_kernel<128, false, true><<<gemm_grid, 256, 0, stream>>>(X, W1h, XW1h, N);

    // CSR build (deterministic counting sort; rows padded to multiples of 8)
    chunk_hist_kernel<<<NCHUNK, 256, 0, stream>>>(erow, counts, E);
    bucket_scan_kernel<<<NB, 512, 0, stream>>>(counts, offnb, tot);
    base_scan_kernel<<<1, 512, 0, stream>>>(tot, bbase);
    coarse_scatter_kernel<<<NCHUNK, 512, 0, stream>>>(erow, ecol, evals, offnb, bbase,
                                                      keyOut, valOut, E);
    fine_sort_kernel<<<NB, 256, 0, stream>>>(keyOut, valOut, bbase, row_ptr, row_len, ep);

    // H = tanh(SpMM(A, XW1))
    spmm1_kernel<<<spmm_grid, 256, 0, stream>>>(ep, row_ptr, row_len, XW1h, Hh);
    // P = f16(H @ W2^T)
    mfma_gemm_kernel<64, false, false><<<gemm_grid, 256, 0, stream>>>(Hh, W2h, Ph, N);
    // out = tanh(SpMM(A, P))
    spmm2_kernel<<<spmm_grid, 256, 0, stream>>>(ep, row_ptr, row_len, (const ushort*)Ph, out);
}

// Round 11
// 200.002 us; speedup vs baseline: 10.5284x; 1.0404x over previous
//
#include <hip/hip_runtime.h>
#include <hip/hip_bf16.h>
#include <hip/hip_fp16.h>

#define N_NODES 100000
#define N_EDGES 1600000
#define DIM_IN 128
#define DIM_OUT 64

#define NB 391      // coarse buckets: row >> 8 (256 rows each; last has 160)
#define NCHUNK 391  // edge chunks
#define CHUNK 4096  // edges per chunk (NCHUNK*CHUNK >= N_EDGES)
#define BCAP 5120   // max edges per bucket (mean 4092, sd ~64)
#define EPCAP 6144  // fixed ep region per bucket (padded total mean ~4990)

typedef unsigned int uint;
typedef unsigned short ushort;
typedef _Float16 half8 __attribute__((ext_vector_type(8)));
typedef float f32x4 __attribute__((ext_vector_type(4)));

__device__ inline ushort f2h(float f) {
    __half h = __float2half(f);  // round-to-nearest-even
    return *reinterpret_cast<ushort*>(&h);
}

// ---------------- CSR build: two-level counting sort, 8-padded rows ----------------

__global__ __launch_bounds__(256) void chunk_hist_kernel(const int* __restrict__ erow,
                                                         int* __restrict__ counts, int E) {
    __shared__ int hist[NB];
    const int t = threadIdx.x, c = blockIdx.x;
    for (int b = t; b < NB; b += 256) hist[b] = 0;
    __syncthreads();
    const int eb = c * CHUNK;
#pragma unroll
    for (int i = 0; i < CHUNK / 256; ++i) {
        int e = eb + i * 256 + t;
        if (e < E) atomicAdd(&hist[erow[e] >> 8], 1);
    }
    __syncthreads();
    for (int b = t; b < NB; b += 256) counts[b * NCHUNK + c] = hist[b];
}

__global__ __launch_bounds__(512) void bucket_scan_kernel(const int* __restrict__ counts,
                                                          int* __restrict__ offnb,
                                                          int* __restrict__ tot) {
    __shared__ int s[512];
    const int b = blockIdx.x, t = threadIdx.x;
    int v = (t < NCHUNK) ? counts[b * NCHUNK + t] : 0;
    s[t] = v;
    __syncthreads();
#pragma unroll
    for (int o = 1; o < 512; o <<= 1) {
        int x = s[t];
        int y = (t >= o) ? s[t - o] : 0;
        __syncthreads();
        s[t] = x + y;
        __syncthreads();
    }
    if (t < NCHUNK) offnb[b * NCHUNK + t] = s[t] - v;
    if (t == 511) tot[b] = s[511];
}

__global__ __launch_bounds__(512) void base_scan_kernel(const int* __restrict__ tot,
                                                        int* __restrict__ bbase) {
    __shared__ int s[512];
    const int t = threadIdx.x;
    int v = (t < NB) ? tot[t] : 0;
    s[t] = v;
    __syncthreads();
#pragma unroll
    for (int o = 1; o < 512; o <<= 1) {
        int x = s[t];
        int y = (t >= o) ? s[t - o] : 0;
        __syncthreads();
        s[t] = x + y;
        __syncthreads();
    }
    if (t < NB) bbase[t] = s[t] - v;
    if (t == 511) bbase[NB] = s[511];
}

__global__ __launch_bounds__(512) void coarse_scatter_kernel(const int* __restrict__ erow,
                                                             const int* __restrict__ ecol,
                                                             const float* __restrict__ eval,
                                                             const int* __restrict__ offnb,
                                                             const int* __restrict__ bbase,
                                                             uint* __restrict__ keyOut,
                                                             float* __restrict__ valOut, int E) {
    __shared__ int hist[NB];
    __shared__ int segOff[NB];
    __shared__ int localOff[NB];
    __shared__ int sc[512];
    __shared__ int idxL[CHUNK];
    __shared__ int gaddrL[CHUNK];

    const int t = threadIdx.x, c = blockIdx.x;
    for (int b = t; b < NB; b += 512) {
        hist[b] = 0;
        segOff[b] = bbase[b] + offnb[b * NCHUNK + c];
    }
    __syncthreads();
    const int eb = c * CHUNK;
    uint bq[CHUNK / 512];
#pragma unroll
    for (int i = 0; i < CHUNK / 512; ++i) {
        int e = eb + i * 512 + t;
        if (e < E) {
            int b = erow[e] >> 8;
            int q = atomicAdd(&hist[b], 1);
            bq[i] = ((uint)b << 16) | (uint)q;
        } else {
            bq[i] = 0xFFFFFFFFu;
        }
    }
    __syncthreads();
    int v = (t < NB) ? hist[t] : 0;
    sc[t] = v;
    __syncthreads();
#pragma unroll
    for (int o = 1; o < 512; o <<= 1) {
        int x = sc[t];
        int y = (t >= o) ? sc[t - o] : 0;
        __syncthreads();
        sc[t] = x + y;
        __syncthreads();
    }
    if (t < NB) localOff[t] = sc[t] - v;
    __syncthreads();
#pragma unroll
    for (int i = 0; i < CHUNK / 512; ++i) {
        if (bq[i] != 0xFFFFFFFFu) {
            int b = bq[i] >> 16;
            int q = bq[i] & 0xFFFF;
            int s = localOff[b] + q;
            idxL[s] = eb + i * 512 + t;
            gaddrL[s] = segOff[b] + q;
        }
    }
    __syncthreads();
    const int m = min(CHUNK, E - eb);
    for (int s = t; s < m; s += 512) {
        int e = idxL[s];
        int g = gaddrL[s];
        keyOut[g] = ((uint)(erow[e] & 255) << 17) | (uint)ecol[e];
        valOut[g] = eval[e];
    }
}

// Fine sort: per-bucket 256-bin counting sort by row; rows padded to multiples of 8.
__global__ __launch_bounds__(256) void fine_sort_kernel(const uint* __restrict__ keyOut,
                                                        const float* __restrict__ valOut,
                                                        const int* __restrict__ bbase,
                                                        int* __restrict__ row_ptr,
                                                        int* __restrict__ row_len,
                                                        int2* __restrict__ ep) {
    __shared__ uint keyL[BCAP];
    __shared__ int hist[256];
    __shared__ int offs[256];
    const int b = blockIdx.x, t = threadIdx.x;
    const int s0 = bbase[b], s1 = bbase[b + 1];
    const int m = min(s1 - s0, BCAP);
    hist[t] = 0;
    __syncthreads();
    for (int j = t; j < m; j += 256) {
        uint k = keyOut[s0 + j];
        keyL[j] = k;
        atomicAdd(&hist[k >> 17], 1);
    }
    __syncthreads();
    const int deg = hist[t];
    const int pdeg = (deg + 7) & ~7;
    offs[t] = pdeg;
    __syncthreads();
#pragma unroll
    for (int o = 1; o < 256; o <<= 1) {
        int x = offs[t];
        int y = (t >= o) ? offs[t - o] : 0;
        __syncthreads();
        offs[t] = x + y;
        __syncthreads();
    }
    const int pexcl = offs[t] - pdeg;
    const int base = b * EPCAP;
    const int row = b * 256 + t;
    if (row < N_NODES) {
        row_ptr[row] = base + pexcl;
        row_len[row] = pdeg;
    }
    hist[t] = pexcl;
    __syncthreads();
    for (int j = t; j < m; j += 256) {
        uint k = keyL[j];
        int pos = atomicAdd(&hist[k >> 17], 1);
        ep[base + pos] = make_int2((int)(k & 0x1FFFFu), __float_as_int(valOut[s0 + j]));
    }
    __syncthreads();
    for (int j = pexcl + deg; j < pexcl + pdeg; ++j)
        ep[base + j] = make_int2(0, 0);
}

// ---------------- f32 -> f16 conversion of both weights in one launch ----------------

__global__ __launch_bounds__(256) void cvt_weights_kernel(const float* __restrict__ W1,
                                                          const float* __restrict__ W2,
                                                          uint* __restrict__ W1h,
                                                          uint* __restrict__ W2h) {
    int i = blockIdx.x * 256 + threadIdx.x;  // 2048 for W1, 1024 for W2
    const float* in;
    uint* outp;
    int j;
    if (i < 2048) { in = W1; outp = W1h; j = i; }
    else if (i < 3072) { in = W2; outp = W2h; j = i - 2048; }
    else return;
    const float4* in4 = reinterpret_cast<const float4*>(in) + (size_t)j * 2;
    float4 a = in4[0];
    float4 b = in4[1];
    uint4 o;
    o.x = (uint)f2h(a.x) | ((uint)f2h(a.y) << 16);
    o.y = (uint)f2h(a.z) | ((uint)f2h(a.w) << 16);
    o.z = (uint)f2h(b.x) | ((uint)f2h(b.y) << 16);
    o.w = (uint)f2h(b.z) | ((uint)f2h(b.w) << 16);
    reinterpret_cast<uint4*>(outp)[j] = o;
}

// ---------------- MFMA GEMM: XW1 = f16(X @ W1^T), K=128, f32 in / f16 out ----------------

__global__ __launch_bounds__(256) void mfma_gemm128_kernel(const float* __restrict__ Af,
                                                           const uint* __restrict__ Wh,
                                                           uint* __restrict__ Out, int M) {
    __shared__ __align__(16) ushort sA[128 * 128];
    __shared__ __align__(16) ushort sB[128 * 128];

    const int t = threadIdx.x;
    const int l = t & 63;
    const int w = t >> 6;
    const int row0 = blockIdx.x * 128;
    const int lr = l & 15;
    const int lk = l >> 4;

#pragma unroll
    for (int i = 0; i < 16; ++i) {
        int fid = i * 256 + t;
        int row = fid >> 5, q4 = fid & 31;
        int gr = row0 + row;
        float4 v = make_float4(0.f, 0.f, 0.f, 0.f);
        if (gr < M) v = *reinterpret_cast<const float4*>(Af + (size_t)gr * 128 + q4 * 4);
        uint2 p;
        p.x = (uint)f2h(v.x) | ((uint)f2h(v.y) << 16);
        p.y = (uint)f2h(v.z) | ((uint)f2h(v.w) << 16);
        int slot = q4 >> 1;
        *reinterpret_cast<uint2*>(&sA[row * 128 + ((slot ^ (row & 7)) << 3) + (q4 & 1) * 4]) = p;
    }
#pragma unroll
    for (int i = 0; i < 8; ++i) {
        int fid = i * 256 + t;
        int row = fid >> 4, slot = fid & 15;
        uint4 v = reinterpret_cast<const uint4*>(Wh)[row * 16 + slot];
        *reinterpret_cast<uint4*>(&sB[row * 128 + ((slot ^ (row & 7)) << 3)]) = v;
    }
    __syncthreads();

    f32x4 acc[2][8];
#pragma unroll
    for (int rf = 0; rf < 2; ++rf)
#pragma unroll
        for (int cf = 0; cf < 8; ++cf) acc[rf][cf] = (f32x4){0.f, 0.f, 0.f, 0.f};

    half8 aF[2][4];
#pragma unroll
    for (int rf = 0; rf < 2; ++rf) {
        int row = w * 32 + rf * 16 + lr;
#pragma unroll
        for (int kc = 0; kc < 4; ++kc) {
            int slot = kc * 4 + lk;
            aF[rf][kc] = *reinterpret_cast<const half8*>(&sA[row * 128 + ((slot ^ (row & 7)) << 3)]);
        }
    }
#pragma unroll
    for (int cf = 0; cf < 8; ++cf) {
        int col = cf * 16 + lr;
#pragma unroll
        for (int kc = 0; kc < 4; ++kc) {
            int slot = kc * 4 + lk;
            half8 bF = *reinterpret_cast<const half8*>(&sB[col * 128 + ((slot ^ (col & 7)) << 3)]);
            acc[0][cf] = __builtin_amdgcn_mfma_f32_16x16x32_f16(aF[0][kc], bF, acc[0][cf], 0, 0, 0);
            acc[1][cf] = __builtin_amdgcn_mfma_f32_16x16x32_f16(aF[1][kc], bF, acc[1][cf], 0, 0, 0);
        }
    }
    __syncthreads();

    ushort* sOut = sA;
#pragma unroll
    for (int rf = 0; rf < 2; ++rf)
#pragma unroll
        for (int cf = 0; cf < 8; ++cf)
#pragma unroll
            for (int reg = 0; reg < 4; ++reg) {
                int row = w * 32 + rf * 16 + lk * 4 + reg;
                int col = cf * 16 + lr;
                sOut[row * 128 + col] = f2h(acc[rf][cf][reg]);
            }
    __syncthreads();
#pragma unroll
    for (int i = 0; i < 8; ++i) {
        int fid = i * 256 + t;
        int row = fid >> 4, q = fid & 15;
        int gr = row0 + row;
        if (gr < M)
            reinterpret_cast<uint4*>(Out)[(size_t)gr * 16 + q] =
                *reinterpret_cast<const uint4*>(&sOut[row * 128 + q * 8]);
    }
}

// ---------------- Fused SpMM1 + MLP2: P = tanh(SpMM(A,XW1)) @ W2^T ----------------
// 16 rows/block, 4 waves x 4 rows. Gather accumulates H (tanh'd, f16) into swizzled
// LDS; MFMA phase: wave w computes P[0:16, w*16:(w+1)*16] against staged W2.

__global__ __launch_bounds__(256) void spmm1_fused_kernel(const int2* __restrict__ ep,
                                                          const int* __restrict__ row_ptr,
                                                          const int* __restrict__ row_len,
                                                          const uint* __restrict__ T,
                                                          const uint* __restrict__ W2h,
                                                          uint* __restrict__ Ph, int M) {
    __shared__ __align__(16) ushort sH[16 * 128];   // 4 KB, slot^(row&7) swizzled
    __shared__ __align__(16) ushort sW2[64 * 128];  // 16 KB, swizzled
    __shared__ __align__(16) ushort sP[16 * 64];    // 2 KB, row-major

    const int t = threadIdx.x;
    const int l = t & 63;
    const int w = t >> 6;
    const int lr = l & 15;
    const int lk = l >> 4;
    const int row0 = blockIdx.x * 16;

    // stage W2 (swizzled like mfma_gemm's sB)
#pragma unroll
    for (int i = 0; i < 4; ++i) {
        int fid = i * 256 + t;
        int row = fid >> 4, slot = fid & 15;
        uint4 v = reinterpret_cast<const uint4*>(W2h)[row * 16 + slot];
        *reinterpret_cast<uint4*>(&sW2[row * 128 + ((slot ^ (row & 7)) << 3)]) = v;
    }

    // gather phase: wave w handles local rows w*4 .. w*4+3
    uint* sHu = reinterpret_cast<uint*>(sH);
#pragma unroll
    for (int rr = 0; rr < 4; ++rr) {
        const int lrow = w * 4 + rr;
        const int r = row0 + lrow;
        float a0x = 0.f, a0y = 0.f, a1x = 0.f, a1y = 0.f;
        if (r < M) {
            int beg = row_ptr[r];
            int end = beg + row_len[r];
            for (int e = beg; e < end; e += 8) {
                int2 cv[8];
                uint xu[8];
#pragma unroll
                for (int i = 0; i < 8; ++i) cv[i] = ep[e + i];
#pragma unroll
                for (int i = 0; i < 8; ++i) xu[i] = T[(size_t)cv[i].x * 64 + l];
#pragma unroll
                for (int i = 0; i < 8; ++i) {
                    float v = __int_as_float(cv[i].y);
                    __half2 h2 = *reinterpret_cast<__half2*>(&xu[i]);
                    float2 f = __half22float2(h2);
                    if (i & 1) { a1x += v * f.x; a1y += v * f.y; }
                    else       { a0x += v * f.x; a0y += v * f.y; }
                }
            }
        }
        // lane l holds dims 2l, 2l+1 of H row lrow -> slot l>>2, uint pos l&3
        uint hv = (uint)f2h(tanhf(a0x + a1x)) | ((uint)f2h(tanhf(a0y + a1y)) << 16);
        int slot = l >> 2;
        sHu[lrow * 64 + ((slot ^ (lrow & 7)) << 2) + (l & 3)] = hv;
    }
    __syncthreads();

    // MFMA phase: wave w -> P[0:16, w*16 .. w*16+15]
    f32x4 acc = (f32x4){0.f, 0.f, 0.f, 0.f};
    const int col = w * 16 + lr;
#pragma unroll
    for (int kc = 0; kc < 4; ++kc) {
        int slot = kc * 4 + lk;
        half8 aF = *reinterpret_cast<const half8*>(&sH[lr * 128 + ((slot ^ (lr & 7)) << 3)]);
        half8 bF = *reinterpret_cast<const half8*>(&sW2[col * 128 + ((slot ^ (col & 7)) << 3)]);
        acc = __builtin_amdgcn_mfma_f32_16x16x32_f16(aF, bF, acc, 0, 0, 0);
    }
    // C layout: col = l&15, row = (l>>4)*4 + reg
#pragma unroll
    for (int reg = 0; reg < 4; ++reg) {
        int row = lk * 4 + reg;
        sP[row * 64 + col] = f2h(acc[reg]);
    }
    __syncthreads();

    // coalesced copy-out: 16 rows x 8 uint4
    if (t < 128) {
        int row = t >> 3, q = t & 7;
        int gr = row0 + row;
        if (gr < M)
            reinterpret_cast<uint4*>(Ph)[(size_t)gr * 8 + q] =
                *reinterpret_cast<const uint4*>(&sP[row * 64 + q * 8]);
    }
}

// ---------------- SpMM 64-dim f16 gather + tanh -> f32 out (tail-free) ----------------

__global__ __launch_bounds__(256) void spmm2_kernel(const int2* __restrict__ ep,
                                                    const int* __restrict__ row_ptr,
                                                    const int* __restrict__ row_len,
                                                    const ushort* __restrict__ Ph,
                                                    float* __restrict__ out) {
    int wave = threadIdx.x >> 6;
    int lane = threadIdx.x & 63;
    int r = blockIdx.x * 4 + wave;
    if (r >= N_NODES) return;
    int beg = row_ptr[r];
    int end = beg + row_len[r];
    float acc0 = 0.f, acc1 = 0.f;
    for (int e = beg; e < end; e += 8) {
        int2 cv[8];
        ushort xu[8];
#pragma unroll
        for (int i = 0; i < 8; ++i) cv[i] = ep[e + i];
#pragma unroll
        for (int i = 0; i < 8; ++i) xu[i] = Ph[(size_t)cv[i].x * 64 + lane];
#pragma unroll
        for (int i = 0; i < 8; ++i) {
            float v = __int_as_float(cv[i].y);
            __half h = *reinterpret_cast<__half*>(&xu[i]);
            float x = __half2float(h);
            if (i & 1) acc1 += v * x;
            else       acc0 += v * x;
        }
    }
    out[(size_t)r * DIM_OUT + lane] = tanhf(acc0 + acc1);
}

// ---------------- launch ----------------

extern "C" void kernel_launch(void* const* d_in, const int* in_sizes, int n_in,
                              void* d_out, int out_size, void* d_ws, size_t ws_size,
                              hipStream_t stream) {
    const float* X = (const float*)d_in[0];
    const float* W1 = (const float*)d_in[1];
    const float* W2 = (const float*)d_in[2];
    const float* evals = (const float*)d_in[3];
    const int* erow = (const int*)d_in[4];
    const int* ecol = (const int*)d_in[5];
    float* out = (float*)d_out;

    const int N = N_NODES;
    const int E = N_EDGES;

    char* ws = (char*)d_ws;
    size_t off = 0;
    auto alloc = [&](size_t bytes) {
        size_t o = off;
        off = (off + bytes + 255) & ~(size_t)255;
        return o;
    };
    size_t o_counts = alloc((size_t)NB * NCHUNK * 4);
    size_t o_offnb = alloc((size_t)NB * NCHUNK * 4);
    size_t o_tot = alloc((size_t)NB * 4);
    size_t o_bbase = alloc((size_t)(NB + 1) * 4);
    size_t o_rowptr = alloc((size_t)N * 4);
    size_t o_rowlen = alloc((size_t)N * 4);
    size_t o_ep = alloc((size_t)NB * EPCAP * 8);  // 19.2MB padded CSR
    size_t o_key = alloc((size_t)E * 4);
    size_t o_val = alloc((size_t)E * 4);
    size_t o_xw1 = alloc((size_t)N * 64 * 4);  // XW1h [N,128] f16
    size_t o_ph = alloc((size_t)N * 32 * 4);   // Ph   [N,64]  f16
    size_t o_w1h = alloc((size_t)128 * 64 * 4);
    size_t o_w2h = alloc((size_t)64 * 64 * 4);
    (void)ws_size;

    int* counts = (int*)(ws + o_counts);
    int* offnb = (int*)(ws + o_offnb);
    int* tot = (int*)(ws + o_tot);
    int* bbase = (int*)(ws + o_bbase);
    int* row_ptr = (int*)(ws + o_rowptr);
    int* row_len = (int*)(ws + o_rowlen);
    int2* ep = (int2*)(ws + o_ep);
    uint* keyOut = (uint*)(ws + o_key);
    float* valOut = (float*)(ws + o_val);
    uint* XW1h = (uint*)(ws + o_xw1);
    uint* Ph = (uint*)(ws + o_ph);
    uint* W1h = (uint*)(ws + o_w1h);
    uint* W2h = (uint*)(ws + o_w2h);

    const int gemm_grid = (N + 127) / 128;  // 782
    const int spmm2_grid = (N + 3) / 4;     // 25000
    const int fused_grid = (N + 15) / 16;   // 6250

    // weight conversions (one launch) + XW1 = f16(X @ W1^T)
    cvt_weights_kernel<<<12, 256, 0, stream>>>(W1, W2, W1h, W2h);
    mfma_gemm128_kernel<<<gemm_grid, 256, 0, stream>>>(X, W1h, XW1h, N);

    // CSR build (deterministic counting sort; rows padded to multiples of 8)
    chunk_hist_kernel<<<NCHUNK, 256, 0, stream>>>(erow, counts, E);
    bucket_scan_kernel<<<NB, 512, 0, stream>>>(counts, offnb, tot);
    base_scan_kernel<<<1, 512, 0, stream>>>(tot, bbase);
    coarse_scatter_kernel<<<NCHUNK, 512, 0, stream>>>(erow, ecol, evals, offnb, bbase,
                                                      keyOut, valOut, E);
    fine_sort_kernel<<<NB, 256, 0, stream>>>(keyOut, valOut, bbase, row_ptr, row_len, ep);

    // P = tanh(SpMM(A, XW1)) @ W2^T   [fused]
    spmm1_fused_kernel<<<fused_grid, 256, 0, stream>>>(ep, row_ptr, row_len, XW1h, W2h, Ph, N);
    // out = tanh(SpMM(A, P))
    spmm2_kernel<<<spmm2_grid, 256, 0, stream>>>(ep, row_ptr, row_len, (const ushort*)Ph, out);
}